// Round 1
// baseline (2388.388 us; speedup 1.0000x reference)
//
#include <hip/hip_runtime.h>

#define NPTS 12288
#define LQPAD 1800
#define EPSBN 1e-4f

// ---------------- small GEMM: C[n,64] = A[n,64] @ W[64,64] ----------------
// 16 rows/block, W transposed in LDS, 4-row register blocking. In-place safe (C may == A).
__global__ __launch_bounds__(256) void gemm64(const float* A, const float* __restrict__ W,
                                              float* C, int n) {
    __shared__ __align__(16) float Wt[64 * 68];   // Wt[o][f_in], stride 68
    __shared__ __align__(16) float As[16][64];
    int t = threadIdx.x;
    int f = t & 63, rg = t >> 6;
    int row0 = blockIdx.x * 16;
    for (int i = t; i < 4096; i += 256) {
        int c = i >> 6, ff = i & 63;
        Wt[ff * 68 + c] = W[i];
    }
    for (int rr = rg; rr < 16; rr += 4) As[rr][f] = A[(row0 + rr) * 64 + f];
    __syncthreads();
    float acc[4] = {0.f, 0.f, 0.f, 0.f};
    const float* wrow = Wt + f * 68;
#pragma unroll
    for (int cq = 0; cq < 64; cq += 4) {
        float4 wq = *(const float4*)(wrow + cq);
#pragma unroll
        for (int rr = 0; rr < 4; rr++) {
            float4 aq = *(const float4*)(&As[rg * 4 + rr][cq]);
            acc[rr] += aq.x * wq.x + aq.y * wq.y + aq.z * wq.z + aq.w * wq.w;
        }
    }
#pragma unroll
    for (int rr = 0; rr < 4; rr++) C[(row0 + rg * 4 + rr) * 64 + f] = acc[rr];
}

// ---------------- gather conv: OUT[i] = sum_k mask * X[idx[i,k]] @ W[k] ----------------
__global__ __launch_bounds__(256) void gconv(const float* __restrict__ X, const int* __restrict__ idx,
                                             const float* __restrict__ W, float* __restrict__ OUT,
                                             int n, int nk) {
    __shared__ __align__(16) float Wt[64 * 68];
    __shared__ __align__(16) float As[16][64];
    int t = threadIdx.x;
    int f = t & 63, rg = t >> 6;
    int row0 = blockIdx.x * 16;
    float acc[4] = {0.f, 0.f, 0.f, 0.f};
    for (int k = 0; k < nk; k++) {
        __syncthreads();
        const float* Wk = W + k * 4096;
        for (int i = t; i < 4096; i += 256) {
            int c = i >> 6, ff = i & 63;
            Wt[ff * 68 + c] = Wk[i];
        }
        for (int rr = rg; rr < 16; rr += 4) {
            int j = idx[(row0 + rr) * nk + k];
            As[rr][f] = (j >= 0) ? X[j * 64 + f] : 0.f;
        }
        __syncthreads();
        const float* wrow = Wt + f * 68;
#pragma unroll
        for (int cq = 0; cq < 64; cq += 4) {
            float4 wq = *(const float4*)(wrow + cq);
#pragma unroll
            for (int rr = 0; rr < 4; rr++) {
                float4 aq = *(const float4*)(&As[rg * 4 + rr][cq]);
                acc[rr] += aq.x * wq.x + aq.y * wq.y + aq.z * wq.z + aq.w * wq.w;
            }
        }
    }
#pragma unroll
    for (int rr = 0; rr < 4; rr++) OUT[(row0 + rg * 4 + rr) * 64 + f] = acc[rr];
}

// ---------------- BN statistics: sum & sumsq per feature (atomic accumulate) ----------------
__global__ __launch_bounds__(256) void bn_stats(const float* __restrict__ X, const float* __restrict__ X2,
                                                float* __restrict__ stats, int n) {
    int t = threadIdx.x;
    int f = t & 63, g = t >> 6;
    float s = 0.f, ss = 0.f;
    for (int r = blockIdx.x * 4 + g; r < n; r += gridDim.x * 4) {
        float v = X[r * 64 + f];
        if (X2) v += X2[r * 64 + f];
        s += v;
        ss += v * v;
    }
    __shared__ float sh[2][4][64];
    sh[0][g][f] = s;
    sh[1][g][f] = ss;
    __syncthreads();
    if (g == 0) {
        s = sh[0][0][f] + sh[0][1][f] + sh[0][2][f] + sh[0][3][f];
        ss = sh[1][0][f] + sh[1][1][f] + sh[1][2][f] + sh[1][3][f];
        atomicAdd(&stats[f], s);
        atomicAdd(&stats[64 + f], ss);
    }
}

// OUT = maybeRelu( BN(X [+ X2]) + (R ? R : 0) )
__global__ __launch_bounds__(256) void bn_apply(const float* __restrict__ X, const float* __restrict__ X2,
                                                const float* R, float* OUT,
                                                const float* __restrict__ stats,
                                                const float* __restrict__ gamma,
                                                const float* __restrict__ beta, int n, int do_relu) {
    int i = blockIdx.x * 256 + threadIdx.x;
    if (i >= n * 64) return;
    int f = i & 63;
    float inv_n = 1.f / (float)n;
    float mean = stats[f] * inv_n;
    float var = stats[64 + f] * inv_n - mean * mean;
    float rstd = rsqrtf(var + EPSBN);
    float v = X[i];
    if (X2) v += X2[i];
    v = (v - mean) * rstd * gamma[f] + beta[f];
    if (R) v += R[i];
    if (do_relu) v = fmaxf(v, 0.f);
    OUT[i] = v;
}

// ---------------- Stage-1 flash attention: O = softmax(Q K^T) V (global, no scale) ----------
// 16 query rows/block (4 per wave), 64-key tiles.
__global__ __launch_bounds__(256) void flash1(const float* __restrict__ Q, const float* __restrict__ K,
                                              const float* __restrict__ V, float* __restrict__ O,
                                              int nk) {
    __shared__ __align__(16) float Ks[64 * 68];  // [key][c]
    __shared__ __align__(16) float Vt[64 * 68];  // [f][key]
    __shared__ __align__(16) float Qs[16 * 64];
    __shared__ __align__(16) float Ps[4][4][64];
    int t = threadIdx.x;
    int lane = t & 63, wv = t >> 6;
    int row0 = blockIdx.x * 16;
    for (int i = t; i < 16 * 64; i += 256) Qs[i] = Q[row0 * 64 + i];
    float m_i[4] = {-1e30f, -1e30f, -1e30f, -1e30f};
    float l_i[4] = {0.f, 0.f, 0.f, 0.f};
    float acc[4] = {0.f, 0.f, 0.f, 0.f};
    int j = t >> 2, c0 = (t & 3) * 16;
    for (int k0 = 0; k0 < nk; k0 += 64) {
        __syncthreads();
        {
            const float* ksrc = K + (size_t)(k0 + j) * 64 + c0;
            float* kdst = Ks + j * 68 + c0;
#pragma unroll
            for (int u = 0; u < 16; u += 4) *(float4*)(kdst + u) = *(const float4*)(ksrc + u);
            const float* vsrc = V + (size_t)(k0 + j) * 64 + c0;
#pragma unroll
            for (int u = 0; u < 16; u += 4) {
                float4 vv = *(const float4*)(vsrc + u);
                Vt[(c0 + u + 0) * 68 + j] = vv.x;
                Vt[(c0 + u + 1) * 68 + j] = vv.y;
                Vt[(c0 + u + 2) * 68 + j] = vv.z;
                Vt[(c0 + u + 3) * 68 + j] = vv.w;
            }
        }
        __syncthreads();
        float s[4] = {0.f, 0.f, 0.f, 0.f};
        const float* krow = Ks + lane * 68;
        const float* q0 = Qs + (wv * 4) * 64;
#pragma unroll
        for (int cq = 0; cq < 64; cq += 4) {
            float4 kq = *(const float4*)(krow + cq);
#pragma unroll
            for (int rr = 0; rr < 4; rr++) {
                float4 qq = *(const float4*)(q0 + rr * 64 + cq);
                s[rr] += qq.x * kq.x + qq.y * kq.y + qq.z * kq.z + qq.w * kq.w;
            }
        }
#pragma unroll
        for (int rr = 0; rr < 4; rr++) {
            float sm = s[rr];
            for (int off = 32; off > 0; off >>= 1) sm = fmaxf(sm, __shfl_xor(sm, off));
            float m_new = fmaxf(m_i[rr], sm);
            float p = __expf(s[rr] - m_new);
            float ps = p;
            for (int off = 32; off > 0; off >>= 1) ps += __shfl_xor(ps, off);
            float alpha = __expf(m_i[rr] - m_new);
            l_i[rr] = l_i[rr] * alpha + ps;
            m_i[rr] = m_new;
            Ps[wv][rr][lane] = p;
            acc[rr] *= alpha;
        }
        __syncthreads();
        const float* vrow = Vt + lane * 68;
#pragma unroll
        for (int jq = 0; jq < 64; jq += 4) {
            float4 vv = *(const float4*)(vrow + jq);
#pragma unroll
            for (int rr = 0; rr < 4; rr++) {
                float4 pp = *(const float4*)(&Ps[wv][rr][jq]);
                acc[rr] += pp.x * vv.x + pp.y * vv.y + pp.z * vv.z + pp.w * vv.w;
            }
        }
    }
#pragma unroll
    for (int rr = 0; rr < 4; rr++) O[(row0 + wv * 4 + rr) * 64 + lane] = acc[rr] / l_i[rr];
}

// ---------------- Stage-2 ragged per-batch flash attention ----------------
// grid.y = batch; rows/keys addressed through pad_idx (−1 = invalid → exact −1e30 masking).
__global__ __launch_bounds__(256) void flash2(const float* __restrict__ Q, const float* __restrict__ K,
                                              const float* __restrict__ V, const int* __restrict__ pad_idx,
                                              float* __restrict__ O) {
    __shared__ __align__(16) float Ks[64 * 68];
    __shared__ __align__(16) float Vt[64 * 68];
    __shared__ __align__(16) float Qs[16 * 64];
    __shared__ __align__(16) float Ps[4][4][64];
    __shared__ int validS[64];
    int t = threadIdx.x;
    int lane = t & 63, wv = t >> 6;
    int b = blockIdx.y;
    const int* prow = pad_idx + b * LQPAD;
    int p0 = blockIdx.x * 16;
    for (int i = t; i < 16 * 64; i += 256) {
        int r = i >> 6, c = i & 63;
        int p = p0 + r;
        int flat = (p < LQPAD) ? prow[p] : -1;
        Qs[i] = (flat >= 0) ? Q[flat * 64 + c] : 0.f;
    }
    float m_i[4] = {-1e30f, -1e30f, -1e30f, -1e30f};
    float l_i[4] = {0.f, 0.f, 0.f, 0.f};
    float acc[4] = {0.f, 0.f, 0.f, 0.f};
    int j = t >> 2, c0 = (t & 3) * 16;
    for (int m0 = 0; m0 < LQPAD; m0 += 64) {
        __syncthreads();
        {
            int m = m0 + j;
            int flat = (m < LQPAD) ? prow[m] : -1;
            if (c0 == 0) validS[j] = (flat >= 0);
            float* kdst = Ks + j * 68 + c0;
            if (flat >= 0) {
                const float* ksrc = K + (size_t)flat * 64 + c0;
#pragma unroll
                for (int u = 0; u < 16; u += 4) *(float4*)(kdst + u) = *(const float4*)(ksrc + u);
                const float* vsrc = V + (size_t)flat * 64 + c0;
#pragma unroll
                for (int u = 0; u < 16; u += 4) {
                    float4 vv = *(const float4*)(vsrc + u);
                    Vt[(c0 + u + 0) * 68 + j] = vv.x;
                    Vt[(c0 + u + 1) * 68 + j] = vv.y;
                    Vt[(c0 + u + 2) * 68 + j] = vv.z;
                    Vt[(c0 + u + 3) * 68 + j] = vv.w;
                }
            } else {
#pragma unroll
                for (int u = 0; u < 16; u++) {
                    kdst[u] = 0.f;
                    Vt[(c0 + u) * 68 + j] = 0.f;
                }
            }
        }
        __syncthreads();
        int kvalid = validS[lane];
        float s[4] = {0.f, 0.f, 0.f, 0.f};
        const float* krow = Ks + lane * 68;
        const float* q0 = Qs + (wv * 4) * 64;
#pragma unroll
        for (int cq = 0; cq < 64; cq += 4) {
            float4 kq = *(const float4*)(krow + cq);
#pragma unroll
            for (int rr = 0; rr < 4; rr++) {
                float4 qq = *(const float4*)(q0 + rr * 64 + cq);
                s[rr] += qq.x * kq.x + qq.y * kq.y + qq.z * kq.z + qq.w * kq.w;
            }
        }
#pragma unroll
        for (int rr = 0; rr < 4; rr++) {
            float sv = kvalid ? s[rr] : -1e30f;
            float sm = sv;
            for (int off = 32; off > 0; off >>= 1) sm = fmaxf(sm, __shfl_xor(sm, off));
            float m_new = fmaxf(m_i[rr], sm);
            float p = __expf(sv - m_new);
            float ps = p;
            for (int off = 32; off > 0; off >>= 1) ps += __shfl_xor(ps, off);
            float alpha = __expf(m_i[rr] - m_new);
            l_i[rr] = l_i[rr] * alpha + ps;
            m_i[rr] = m_new;
            Ps[wv][rr][lane] = p;
            acc[rr] *= alpha;
        }
        __syncthreads();
        const float* vrow = Vt + lane * 68;
#pragma unroll
        for (int jq = 0; jq < 64; jq += 4) {
            float4 vv = *(const float4*)(vrow + jq);
#pragma unroll
            for (int rr = 0; rr < 4; rr++) {
                float4 pp = *(const float4*)(&Ps[wv][rr][jq]);
                acc[rr] += pp.x * vv.x + pp.y * vv.y + pp.z * vv.z + pp.w * vv.w;
            }
        }
    }
#pragma unroll
    for (int rr = 0; rr < 4; rr++) {
        int p = p0 + wv * 4 + rr;
        int flat = (p < LQPAD) ? prow[p] : -1;
        if (flat >= 0) O[flat * 64 + lane] = acc[rr] / l_i[rr];
    }
}

extern "C" void kernel_launch(void* const* d_in, const int* in_sizes, int n_in,
                              void* d_out, int out_size, void* d_ws, size_t ws_size,
                              hipStream_t stream) {
    const float* x_dec = (const float*)d_in[0];
    const float* x_enc = (const float*)d_in[1];
    const float* Wp1 = (const float*)d_in[2];
    const float* Wq = (const float*)d_in[3];
    const float* Wk = (const float*)d_in[4];
    const float* Wv = (const float*)d_in[5];
    const float* Wt_ = (const float*)d_in[6];
    const float* Wq1 = (const float*)d_in[7];
    const float* Wk1 = (const float*)d_in[8];
    const float* Wv1 = (const float*)d_in[9];
    const float* Wdown = (const float*)d_in[10];
    const float* W3t = (const float*)d_in[11];
    const float* W3a = (const float*)d_in[12];
    const float* W3b = (const float*)d_in[13];
    const float* bn_g = (const float*)d_in[14];
    const float* bn_b = (const float*)d_in[15];
    const int* nbr = (const int*)d_in[16];
    const int* kv_nbr = (const int*)d_in[17];
    const int* pad_idx = (const int*)d_in[18];
    float* out = (float*)d_out;
    float* ws = (float*)d_ws;

    const int N = NPTS;
    const size_t BUF = (size_t)N * 64;
    float* xd = ws;
    float* q = ws + BUF;       // q, later q1
    float* ke = ws + 2 * BUF;  // ke, later k1
    float* ve = ws + 3 * BUF;  // ve, later v1
    float* xr = ws + 4 * BUF;  // attn1 out / xr@Wt / relu-bn3 temp
    float* kv = ws + 5 * BUF;
    float* o2 = ws + 6 * BUF;  // stage-2 out / z
    float* xr2 = ws + 7 * BUF; // conv27 out / relu-bn4 temp
    float* z2 = ws + 8 * BUF;
    float* stats = ws + 9 * BUF;  // 6 slots x 128 floats

    hipMemsetAsync(stats, 0, 6 * 128 * sizeof(float), stream);

    dim3 B(256);
    int gR = N / 16;            // 768: row-tiled kernels
    int gS = 64;                // bn stats
    int gE = (N * 64) / 256;    // 3072: elementwise

    gemm64<<<gR, B, 0, stream>>>(x_dec, Wp1, xd, N);
    gemm64<<<gR, B, 0, stream>>>(xd, Wq, q, N);
    gemm64<<<gR, B, 0, stream>>>(x_enc, Wk, ke, N);
    gemm64<<<gR, B, 0, stream>>>(x_enc, Wv, ve, N);
    flash1<<<gR, B, 0, stream>>>(q, ke, ve, xr, N);
    gemm64<<<gR, B, 0, stream>>>(xr, Wt_, xr, N);  // in-place, block-safe
    bn_stats<<<gS, B, 0, stream>>>(xr, nullptr, stats + 0, N);
    bn_apply<<<gE, B, 0, stream>>>(xr, nullptr, xd, xd, stats + 0, bn_g + 0, bn_b + 0, N, 0);

    gemm64<<<gR, B, 0, stream>>>(xd, Wq1, q, N);              // q1
    gconv<<<gR, B, 0, stream>>>(q, kv_nbr, Wdown, kv, N, 8);  // stride-2 conv
    bn_stats<<<gS, B, 0, stream>>>(kv, nullptr, stats + 128, N);
    bn_apply<<<gE, B, 0, stream>>>(kv, nullptr, nullptr, kv, stats + 128, bn_g + 64, bn_b + 64, N, 0);
    gemm64<<<gR, B, 0, stream>>>(kv, Wk1, ke, N);  // k1
    gemm64<<<gR, B, 0, stream>>>(kv, Wv1, ve, N);  // v1
    flash2<<<dim3(113, 8), B, 0, stream>>>(q, ke, ve, pad_idx, o2);
    gconv<<<gR, B, 0, stream>>>(o2, nbr, W3t, xr2, N, 27);
    bn_stats<<<gS, B, 0, stream>>>(xr2, nullptr, stats + 256, N);
    bn_apply<<<gE, B, 0, stream>>>(xr2, nullptr, xd, xd, stats + 256, bn_g + 128, bn_b + 128, N, 0);

    // res block
    bn_stats<<<gS, B, 0, stream>>>(xd, nullptr, stats + 384, N);
    bn_apply<<<gE, B, 0, stream>>>(xd, nullptr, nullptr, xr, stats + 384, bn_g + 192, bn_b + 192, N, 1);
    gconv<<<gR, B, 0, stream>>>(xr, nbr, W3a, o2, N, 27);  // z
    bn_stats<<<gS, B, 0, stream>>>(o2, nullptr, stats + 512, N);
    bn_apply<<<gE, B, 0, stream>>>(o2, nullptr, nullptr, xr2, stats + 512, bn_g + 256, bn_b + 256, N, 1);
    gconv<<<gR, B, 0, stream>>>(xr2, nbr, W3b, z2, N, 27);
    bn_stats<<<gS, B, 0, stream>>>(xd, z2, stats + 640, N);
    bn_apply<<<gE, B, 0, stream>>>(xd, z2, nullptr, out, stats + 640, bn_g + 320, bn_b + 320, N, 1);
}

// Round 2
// 1016.215 us; speedup vs baseline: 2.3503x; 2.3503x over previous
//
#include <hip/hip_runtime.h>

#define NPTS 12288
#define LQPAD 1800
#define EPSBN 1e-4f

typedef _Float16 half8 __attribute__((ext_vector_type(8)));
typedef _Float16 half4 __attribute__((ext_vector_type(4)));
typedef float floatx4 __attribute__((ext_vector_type(4)));

// ---------------- small GEMM: C[n,64] = A[n,64] @ W[64,64] ----------------
__global__ __launch_bounds__(256) void gemm64(const float* A, const float* __restrict__ W,
                                              float* C, int n) {
    __shared__ __align__(16) float Wt[64 * 68];
    __shared__ __align__(16) float As[16][64];
    int t = threadIdx.x;
    int f = t & 63, rg = t >> 6;
    int row0 = blockIdx.x * 16;
    for (int i = t; i < 4096; i += 256) {
        int c = i >> 6, ff = i & 63;
        Wt[ff * 68 + c] = W[i];
    }
    for (int rr = rg; rr < 16; rr += 4) As[rr][f] = A[(row0 + rr) * 64 + f];
    __syncthreads();
    float acc[4] = {0.f, 0.f, 0.f, 0.f};
    const float* wrow = Wt + f * 68;
#pragma unroll
    for (int cq = 0; cq < 64; cq += 4) {
        float4 wq = *(const float4*)(wrow + cq);
#pragma unroll
        for (int rr = 0; rr < 4; rr++) {
            float4 aq = *(const float4*)(&As[rg * 4 + rr][cq]);
            acc[rr] += aq.x * wq.x + aq.y * wq.y + aq.z * wq.z + aq.w * wq.w;
        }
    }
#pragma unroll
    for (int rr = 0; rr < 4; rr++) C[(row0 + rg * 4 + rr) * 64 + f] = acc[rr];
}

// ---------------- gather conv ----------------
__global__ __launch_bounds__(256) void gconv(const float* __restrict__ X, const int* __restrict__ idx,
                                             const float* __restrict__ W, float* __restrict__ OUT,
                                             int n, int nk) {
    __shared__ __align__(16) float Wt[64 * 68];
    __shared__ __align__(16) float As[16][64];
    int t = threadIdx.x;
    int f = t & 63, rg = t >> 6;
    int row0 = blockIdx.x * 16;
    float acc[4] = {0.f, 0.f, 0.f, 0.f};
    for (int k = 0; k < nk; k++) {
        __syncthreads();
        const float* Wk = W + k * 4096;
        for (int i = t; i < 4096; i += 256) {
            int c = i >> 6, ff = i & 63;
            Wt[ff * 68 + c] = Wk[i];
        }
        for (int rr = rg; rr < 16; rr += 4) {
            int j = idx[(row0 + rr) * nk + k];
            As[rr][f] = (j >= 0) ? X[j * 64 + f] : 0.f;
        }
        __syncthreads();
        const float* wrow = Wt + f * 68;
#pragma unroll
        for (int cq = 0; cq < 64; cq += 4) {
            float4 wq = *(const float4*)(wrow + cq);
#pragma unroll
            for (int rr = 0; rr < 4; rr++) {
                float4 aq = *(const float4*)(&As[rg * 4 + rr][cq]);
                acc[rr] += aq.x * wq.x + aq.y * wq.y + aq.z * wq.z + aq.w * wq.w;
            }
        }
    }
#pragma unroll
    for (int rr = 0; rr < 4; rr++) OUT[(row0 + rg * 4 + rr) * 64 + f] = acc[rr];
}

// ---------------- BN statistics ----------------
__global__ __launch_bounds__(256) void bn_stats(const float* __restrict__ X, const float* __restrict__ X2,
                                                float* __restrict__ stats, int n) {
    int t = threadIdx.x;
    int f = t & 63, g = t >> 6;
    float s = 0.f, ss = 0.f;
    for (int r = blockIdx.x * 4 + g; r < n; r += gridDim.x * 4) {
        float v = X[r * 64 + f];
        if (X2) v += X2[r * 64 + f];
        s += v;
        ss += v * v;
    }
    __shared__ float sh[2][4][64];
    sh[0][g][f] = s;
    sh[1][g][f] = ss;
    __syncthreads();
    if (g == 0) {
        s = sh[0][0][f] + sh[0][1][f] + sh[0][2][f] + sh[0][3][f];
        ss = sh[1][0][f] + sh[1][1][f] + sh[1][2][f] + sh[1][3][f];
        atomicAdd(&stats[f], s);
        atomicAdd(&stats[64 + f], ss);
    }
}

__global__ __launch_bounds__(256) void bn_apply(const float* __restrict__ X, const float* __restrict__ X2,
                                                const float* R, float* OUT,
                                                const float* __restrict__ stats,
                                                const float* __restrict__ gamma,
                                                const float* __restrict__ beta, int n, int do_relu) {
    int i = blockIdx.x * 256 + threadIdx.x;
    if (i >= n * 64) return;
    int f = i & 63;
    float inv_n = 1.f / (float)n;
    float mean = stats[f] * inv_n;
    float var = stats[64 + f] * inv_n - mean * mean;
    float rstd = rsqrtf(var + EPSBN);
    float v = X[i];
    if (X2) v += X2[i];
    v = (v - mean) * rstd * gamma[f] + beta[f];
    if (R) v += R[i];
    if (do_relu) v = fmaxf(v, 0.f);
    OUT[i] = v;
}

// ---------------- stage-1 prep: fp32 -> fp16 (Q split hi/lo; K direct) ----------------
__global__ __launch_bounds__(256) void prep1(const float* __restrict__ q, const float* __restrict__ k,
                                             _Float16* __restrict__ Qh, _Float16* __restrict__ Ql,
                                             _Float16* __restrict__ Kh) {
    int i = blockIdx.x * 256 + threadIdx.x;
    if (i >= NPTS * 64) return;
    float qv = q[i];
    _Float16 h = (_Float16)qv;
    Qh[i] = h;
    Ql[i] = (_Float16)(qv - (float)h);
    Kh[i] = (_Float16)k[i];
}

// ---------------- V transpose: V[key][f] fp32 -> Vt[f][key] fp16 ----------------
__global__ __launch_bounds__(256) void vtrans(const float* __restrict__ V, _Float16* __restrict__ Vt) {
    __shared__ float T[64][65];
    int t = threadIdx.x;
    int k0 = blockIdx.x * 64;
    for (int idx = t; idx < 4096; idx += 256) {
        int r = idx >> 6, c = idx & 63;
        T[r][c] = V[(k0 + r) * 64 + c];
    }
    __syncthreads();
    int f = t >> 2, ks = (t & 3) * 16;
    half8 a, b;
#pragma unroll
    for (int j = 0; j < 8; j++) {
        a[j] = (_Float16)T[ks + j][f];
        b[j] = (_Float16)T[ks + 8 + j][f];
    }
    *(half8*)(Vt + f * NPTS + k0 + ks) = a;
    *(half8*)(Vt + f * NPTS + k0 + ks + 8) = b;
}

// ---------------- Stage-1 flash attention, MFMA version ----------------
// grid (192, 4): x = 64-query block, y = key split (3072 keys each).
// Per wave: 16 q rows. S^T = K*Qh^T + K*Ql^T (keys on MFMA rows -> cheap softmax
// reduction + packed P^T writes). O^T = V^T * P^T. All LDS ops fragment-major,
// conflict-free. Outputs unnormalized O + (m,l) per split; merge1 combines.
__global__ __launch_bounds__(256) void flash1_mfma(const _Float16* __restrict__ Qh,
                                                   const _Float16* __restrict__ Ql,
                                                   const _Float16* __restrict__ Kh,
                                                   const _Float16* __restrict__ Vt,
                                                   float* __restrict__ Op, float* __restrict__ Ms,
                                                   float* __restrict__ Ls) {
    __shared__ __align__(16) _Float16 KsF[8 * 512];       // 8 frags x 64 lanes x 8 fp16
    __shared__ __align__(16) _Float16 VsF[8 * 512];
    __shared__ __align__(16) _Float16 PTF[4][2 * 512];    // per wave
    int t = threadIdx.x;
    int lane = t & 63, wv = t >> 6;
    int quad = lane >> 4, qi = lane & 15;
    int qb = blockIdx.x, sp = blockIdx.y;
    int q0w = qb * 64 + wv * 16;
    int qrow = q0w + qi;

    half8 qh[2], ql[2];
#pragma unroll
    for (int s = 0; s < 2; s++) {
        qh[s] = *(const half8*)(Qh + qrow * 64 + s * 32 + quad * 8);
        ql[s] = *(const half8*)(Ql + qrow * 64 + s * 32 + quad * 8);
    }
    floatx4 Oacc[4];
#pragma unroll
    for (int ft = 0; ft < 4; ft++) Oacc[ft] = floatx4{0.f, 0.f, 0.f, 0.f};
    float m_i = -1e30f, l_i = 0.f;

    int k0 = sp * 3072;
    for (int it = 0; it < 48; it++, k0 += 64) {
        __syncthreads();
        // cooperative staging: wave w stages frags w, w+4, w+8, w+12 (0..7 K, 8..15 V^T)
#pragma unroll
        for (int u = 0; u < 4; u++) {
            int frag = wv + 4 * u;
            if (frag < 8) {
                int kt = frag >> 1, s = frag & 1;
                int key = k0 + kt * 16 + qi;
                int d0 = s * 32 + quad * 8;
                *(half8*)(KsF + frag * 512 + lane * 8) = *(const half8*)(Kh + key * 64 + d0);
            } else {
                int fr = frag - 8;
                int ft = fr >> 1, s = fr & 1;
                int f = ft * 16 + qi;
                int key = k0 + s * 32 + quad * 8;
                *(half8*)(VsF + fr * 512 + lane * 8) = *(const half8*)(Vt + f * NPTS + key);
            }
        }
        __syncthreads();
        // scores: S^T tiles (16 keys x 16 q), rows = keys
        floatx4 st[4];
#pragma unroll
        for (int kt = 0; kt < 4; kt++) {
            floatx4 acc = floatx4{0.f, 0.f, 0.f, 0.f};
#pragma unroll
            for (int s = 0; s < 2; s++) {
                half8 a = *(const half8*)(KsF + (kt * 2 + s) * 512 + lane * 8);
                acc = __builtin_amdgcn_mfma_f32_16x16x32_f16(a, qh[s], acc, 0, 0, 0);
                acc = __builtin_amdgcn_mfma_f32_16x16x32_f16(a, ql[s], acc, 0, 0, 0);
            }
            st[kt] = acc;
        }
        // online softmax over 64 keys (4 regs x 4 tiles local + xor16/xor32 across quads)
        float mloc = -1e30f;
#pragma unroll
        for (int kt = 0; kt < 4; kt++)
#pragma unroll
            for (int r = 0; r < 4; r++) mloc = fmaxf(mloc, st[kt][r]);
        mloc = fmaxf(mloc, __shfl_xor(mloc, 16));
        mloc = fmaxf(mloc, __shfl_xor(mloc, 32));
        float m_new = fmaxf(m_i, mloc);
        float alpha = __expf(m_i - m_new);
        float ps = 0.f;
#pragma unroll
        for (int kt = 0; kt < 4; kt++) {
            half4 pk;
#pragma unroll
            for (int r = 0; r < 4; r++) {
                float p = __expf(st[kt][r] - m_new);
                ps += p;
                pk[r] = (_Float16)p;
            }
            int s = kt >> 1;
            int qd2 = (kt & 1) * 2 + (quad >> 1);
            *(half4*)(&PTF[wv][(s * 64 + qd2 * 16 + qi) * 8 + (quad & 1) * 4]) = pk;
        }
        ps += __shfl_xor(ps, 16);
        ps += __shfl_xor(ps, 32);
        l_i = l_i * alpha + ps;
        m_i = m_new;
#pragma unroll
        for (int ft = 0; ft < 4; ft++) Oacc[ft] *= alpha;
        // PV: O^T = V^T * P^T
        half8 pb[2];
#pragma unroll
        for (int s = 0; s < 2; s++) pb[s] = *(const half8*)(&PTF[wv][(s * 64 + lane) * 8]);
#pragma unroll
        for (int ft = 0; ft < 4; ft++) {
#pragma unroll
            for (int s = 0; s < 2; s++) {
                half8 a = *(const half8*)(VsF + (ft * 2 + s) * 512 + lane * 8);
                Oacc[ft] = __builtin_amdgcn_mfma_f32_16x16x32_f16(a, pb[s], Oacc[ft], 0, 0, 0);
            }
        }
    }
    // epilogue: O^T rows f = ft*16+quad*4+r, col q -> contiguous float4 in O[q][f]
#pragma unroll
    for (int ft = 0; ft < 4; ft++) {
        floatx4 o = Oacc[ft];
        *(floatx4*)(Op + ((size_t)sp * NPTS + q0w + qi) * 64 + ft * 16 + quad * 4) = o;
    }
    if (lane < 16) {
        Ms[sp * NPTS + q0w + lane] = m_i;
        Ls[sp * NPTS + q0w + lane] = l_i;
    }
}

// ---------------- combine key-split partials ----------------
__global__ __launch_bounds__(256) void merge1(const float* __restrict__ Op, const float* __restrict__ Ms,
                                              const float* __restrict__ Ls, float* __restrict__ xr) {
    int i = blockIdx.x * 256 + threadIdx.x;  // 12288*16
    int q = i >> 4, f4 = (i & 15) * 4;
    float m[4], M = -1e30f;
#pragma unroll
    for (int s = 0; s < 4; s++) {
        m[s] = Ms[s * NPTS + q];
        M = fmaxf(M, m[s]);
    }
    float L = 0.f;
    float4 acc = {0.f, 0.f, 0.f, 0.f};
#pragma unroll
    for (int s = 0; s < 4; s++) {
        float w = __expf(m[s] - M);
        L += Ls[s * NPTS + q] * w;
        float4 o = *(const float4*)(Op + ((size_t)s * NPTS + q) * 64 + f4);
        acc.x += o.x * w;
        acc.y += o.y * w;
        acc.z += o.z * w;
        acc.w += o.w * w;
    }
    float inv = 1.f / L;
    float4 r = {acc.x * inv, acc.y * inv, acc.z * inv, acc.w * inv};
    *(float4*)(xr + q * 64 + f4) = r;
}

// ---------------- Stage-2 ragged per-batch flash attention (unchanged) ----------------
__global__ __launch_bounds__(256) void flash2(const float* __restrict__ Q, const float* __restrict__ K,
                                              const float* __restrict__ V, const int* __restrict__ pad_idx,
                                              float* __restrict__ O) {
    __shared__ __align__(16) float Ks[64 * 68];
    __shared__ __align__(16) float Vt[64 * 68];
    __shared__ __align__(16) float Qs[16 * 64];
    __shared__ __align__(16) float Ps[4][4][64];
    __shared__ int validS[64];
    int t = threadIdx.x;
    int lane = t & 63, wv = t >> 6;
    int b = blockIdx.y;
    const int* prow = pad_idx + b * LQPAD;
    int p0 = blockIdx.x * 16;
    for (int i = t; i < 16 * 64; i += 256) {
        int r = i >> 6, c = i & 63;
        int p = p0 + r;
        int flat = (p < LQPAD) ? prow[p] : -1;
        Qs[i] = (flat >= 0) ? Q[flat * 64 + c] : 0.f;
    }
    float m_i[4] = {-1e30f, -1e30f, -1e30f, -1e30f};
    float l_i[4] = {0.f, 0.f, 0.f, 0.f};
    float acc[4] = {0.f, 0.f, 0.f, 0.f};
    int j = t >> 2, c0 = (t & 3) * 16;
    for (int m0 = 0; m0 < LQPAD; m0 += 64) {
        __syncthreads();
        {
            int m = m0 + j;
            int flat = (m < LQPAD) ? prow[m] : -1;
            if (c0 == 0) validS[j] = (flat >= 0);
            float* kdst = Ks + j * 68 + c0;
            if (flat >= 0) {
                const float* ksrc = K + (size_t)flat * 64 + c0;
#pragma unroll
                for (int u = 0; u < 16; u += 4) *(float4*)(kdst + u) = *(const float4*)(ksrc + u);
                const float* vsrc = V + (size_t)flat * 64 + c0;
#pragma unroll
                for (int u = 0; u < 16; u += 4) {
                    float4 vv = *(const float4*)(vsrc + u);
                    Vt[(c0 + u + 0) * 68 + j] = vv.x;
                    Vt[(c0 + u + 1) * 68 + j] = vv.y;
                    Vt[(c0 + u + 2) * 68 + j] = vv.z;
                    Vt[(c0 + u + 3) * 68 + j] = vv.w;
                }
            } else {
#pragma unroll
                for (int u = 0; u < 16; u++) {
                    kdst[u] = 0.f;
                    Vt[(c0 + u) * 68 + j] = 0.f;
                }
            }
        }
        __syncthreads();
        int kvalid = validS[lane];
        float s[4] = {0.f, 0.f, 0.f, 0.f};
        const float* krow = Ks + lane * 68;
        const float* q0 = Qs + (wv * 4) * 64;
#pragma unroll
        for (int cq = 0; cq < 64; cq += 4) {
            float4 kq = *(const float4*)(krow + cq);
#pragma unroll
            for (int rr = 0; rr < 4; rr++) {
                float4 qq = *(const float4*)(q0 + rr * 64 + cq);
                s[rr] += qq.x * kq.x + qq.y * kq.y + qq.z * kq.z + qq.w * kq.w;
            }
        }
#pragma unroll
        for (int rr = 0; rr < 4; rr++) {
            float sv = kvalid ? s[rr] : -1e30f;
            float sm = sv;
            for (int off = 32; off > 0; off >>= 1) sm = fmaxf(sm, __shfl_xor(sm, off));
            float m_new = fmaxf(m_i[rr], sm);
            float p = __expf(sv - m_new);
            float ps = p;
            for (int off = 32; off > 0; off >>= 1) ps += __shfl_xor(ps, off);
            float alpha = __expf(m_i[rr] - m_new);
            l_i[rr] = l_i[rr] * alpha + ps;
            m_i[rr] = m_new;
            Ps[wv][rr][lane] = p;
            acc[rr] *= alpha;
        }
        __syncthreads();
        const float* vrow = Vt + lane * 68;
#pragma unroll
        for (int jq = 0; jq < 64; jq += 4) {
            float4 vv = *(const float4*)(vrow + jq);
#pragma unroll
            for (int rr = 0; rr < 4; rr++) {
                float4 pp = *(const float4*)(&Ps[wv][rr][jq]);
                acc[rr] += pp.x * vv.x + pp.y * vv.y + pp.z * vv.z + pp.w * vv.w;
            }
        }
    }
#pragma unroll
    for (int rr = 0; rr < 4; rr++) {
        int p = p0 + wv * 4 + rr;
        int flat = (p < LQPAD) ? prow[p] : -1;
        if (flat >= 0) O[flat * 64 + lane] = acc[rr] / l_i[rr];
    }
}

extern "C" void kernel_launch(void* const* d_in, const int* in_sizes, int n_in,
                              void* d_out, int out_size, void* d_ws, size_t ws_size,
                              hipStream_t stream) {
    const float* x_dec = (const float*)d_in[0];
    const float* x_enc = (const float*)d_in[1];
    const float* Wp1 = (const float*)d_in[2];
    const float* Wq = (const float*)d_in[3];
    const float* Wk = (const float*)d_in[4];
    const float* Wv = (const float*)d_in[5];
    const float* Wt_ = (const float*)d_in[6];
    const float* Wq1 = (const float*)d_in[7];
    const float* Wk1 = (const float*)d_in[8];
    const float* Wv1 = (const float*)d_in[9];
    const float* Wdown = (const float*)d_in[10];
    const float* W3t = (const float*)d_in[11];
    const float* W3a = (const float*)d_in[12];
    const float* W3b = (const float*)d_in[13];
    const float* bn_g = (const float*)d_in[14];
    const float* bn_b = (const float*)d_in[15];
    const int* nbr = (const int*)d_in[16];
    const int* kv_nbr = (const int*)d_in[17];
    const int* pad_idx = (const int*)d_in[18];
    float* out = (float*)d_out;
    float* ws = (float*)d_ws;

    const int N = NPTS;
    const size_t BUF = (size_t)N * 64;
    float* xd = ws;                // slot 0
    float* q = ws + BUF;           // slot 1: q fp32 (stage1), later q1; also Opart[0]
    float* ke = ws + 2 * BUF;      // slot 2: ke (stage1), Opart[1], later k1
    float* ve = ws + 3 * BUF;      // slot 3: ve (stage1), Opart[2], later v1
    float* xr = ws + 4 * BUF;      // slot 4: Opart[3] then merged attn out
    float* kv = ws + 5 * BUF;      // slot 5: Qh/Ql fp16 (stage1), later kv
    float* o2 = ws + 6 * BUF;      // slot 6: Kh/Vt fp16 (stage1), later o2/z
    float* xr2 = ws + 7 * BUF;     // slot 7
    float* z2 = ws + 8 * BUF;      // slot 8
    float* stats = ws + 9 * BUF;   // slot 9: stats + m/l arrays
    float* Op = q;                 // 4 contiguous split-partials: slots 1..4
    float* Ms = stats + 1024;      // 4*12288
    float* Ls = Ms + 4 * NPTS;

    _Float16* Qh = (_Float16*)kv;
    _Float16* Ql = Qh + BUF;
    _Float16* Kh = (_Float16*)o2;
    _Float16* Vt = Kh + BUF;

    hipMemsetAsync(stats, 0, 6 * 128 * sizeof(float), stream);

    dim3 B(256);
    int gR = N / 16;
    int gS = 64;
    int gE = (N * 64) / 256;

    gemm64<<<gR, B, 0, stream>>>(x_dec, Wp1, xd, N);
    gemm64<<<gR, B, 0, stream>>>(xd, Wq, q, N);
    gemm64<<<gR, B, 0, stream>>>(x_enc, Wk, ke, N);
    gemm64<<<gR, B, 0, stream>>>(x_enc, Wv, ve, N);
    // stage-1 attention: fp16-split MFMA flash, key-split 4 + merge
    prep1<<<gE, B, 0, stream>>>(q, ke, Qh, Ql, Kh);
    vtrans<<<N / 64, B, 0, stream>>>(ve, Vt);
    flash1_mfma<<<dim3(N / 64, 4), B, 0, stream>>>(Qh, Ql, Kh, Vt, Op, Ms, Ls);
    merge1<<<(N * 16) / 256, B, 0, stream>>>(Op, Ms, Ls, xr);
    gemm64<<<gR, B, 0, stream>>>(xr, Wt_, xr, N);
    bn_stats<<<gS, B, 0, stream>>>(xr, nullptr, stats + 0, N);
    bn_apply<<<gE, B, 0, stream>>>(xr, nullptr, xd, xd, stats + 0, bn_g + 0, bn_b + 0, N, 0);

    gemm64<<<gR, B, 0, stream>>>(xd, Wq1, q, N);
    gconv<<<gR, B, 0, stream>>>(q, kv_nbr, Wdown, kv, N, 8);
    bn_stats<<<gS, B, 0, stream>>>(kv, nullptr, stats + 128, N);
    bn_apply<<<gE, B, 0, stream>>>(kv, nullptr, nullptr, kv, stats + 128, bn_g + 64, bn_b + 64, N, 0);
    gemm64<<<gR, B, 0, stream>>>(kv, Wk1, ke, N);
    gemm64<<<gR, B, 0, stream>>>(kv, Wv1, ve, N);
    flash2<<<dim3(113, 8), B, 0, stream>>>(q, ke, ve, pad_idx, o2);
    gconv<<<gR, B, 0, stream>>>(o2, nbr, W3t, xr2, N, 27);
    bn_stats<<<gS, B, 0, stream>>>(xr2, nullptr, stats + 256, N);
    bn_apply<<<gE, B, 0, stream>>>(xr2, nullptr, xd, xd, stats + 256, bn_g + 128, bn_b + 128, N, 0);

    bn_stats<<<gS, B, 0, stream>>>(xd, nullptr, stats + 384, N);
    bn_apply<<<gE, B, 0, stream>>>(xd, nullptr, nullptr, xr, stats + 384, bn_g + 192, bn_b + 192, N, 1);
    gconv<<<gR, B, 0, stream>>>(xr, nbr, W3a, o2, N, 27);
    bn_stats<<<gS, B, 0, stream>>>(o2, nullptr, stats + 512, N);
    bn_apply<<<gE, B, 0, stream>>>(o2, nullptr, nullptr, xr2, stats + 512, bn_g + 256, bn_b + 256, N, 1);
    gconv<<<gR, B, 0, stream>>>(xr2, nbr, W3b, z2, N, 27);
    bn_stats<<<gS, B, 0, stream>>>(xd, z2, stats + 640, N);
    bn_apply<<<gE, B, 0, stream>>>(xd, z2, nullptr, out, stats + 640, bn_g + 320, bn_b + 320, N, 1);
}

// Round 3
// 814.997 us; speedup vs baseline: 2.9305x; 1.2469x over previous
//
#include <hip/hip_runtime.h>

#define NPTS 12288
#define LQPAD 1800
#define LPAD2 1856
#define EPSBN 1e-4f

typedef _Float16 half8 __attribute__((ext_vector_type(8)));
typedef _Float16 half4 __attribute__((ext_vector_type(4)));
typedef float floatx4 __attribute__((ext_vector_type(4)));

// ---------------- small GEMM: C[n,64] = A[n,64] @ W[64,64] ----------------
__global__ __launch_bounds__(256) void gemm64(const float* A, const float* __restrict__ W,
                                              float* C, int n) {
    __shared__ __align__(16) float Wt[64 * 68];
    __shared__ __align__(16) float As[16][64];
    int t = threadIdx.x;
    int f = t & 63, rg = t >> 6;
    int row0 = blockIdx.x * 16;
    for (int i = t; i < 4096; i += 256) {
        int c = i >> 6, ff = i & 63;
        Wt[ff * 68 + c] = W[i];
    }
    for (int rr = rg; rr < 16; rr += 4) As[rr][f] = A[(row0 + rr) * 64 + f];
    __syncthreads();
    float acc[4] = {0.f, 0.f, 0.f, 0.f};
    const float* wrow = Wt + f * 68;
#pragma unroll
    for (int cq = 0; cq < 64; cq += 4) {
        float4 wq = *(const float4*)(wrow + cq);
#pragma unroll
        for (int rr = 0; rr < 4; rr++) {
            float4 aq = *(const float4*)(&As[rg * 4 + rr][cq]);
            acc[rr] += aq.x * wq.x + aq.y * wq.y + aq.z * wq.z + aq.w * wq.w;
        }
    }
#pragma unroll
    for (int rr = 0; rr < 4; rr++) C[(row0 + rg * 4 + rr) * 64 + f] = acc[rr];
}

// ---------------- gather conv ----------------
__global__ __launch_bounds__(256) void gconv(const float* __restrict__ X, const int* __restrict__ idx,
                                             const float* __restrict__ W, float* __restrict__ OUT,
                                             int n, int nk) {
    __shared__ __align__(16) float Wt[64 * 68];
    __shared__ __align__(16) float As[16][64];
    int t = threadIdx.x;
    int f = t & 63, rg = t >> 6;
    int row0 = blockIdx.x * 16;
    float acc[4] = {0.f, 0.f, 0.f, 0.f};
    for (int k = 0; k < nk; k++) {
        __syncthreads();
        const float* Wk = W + k * 4096;
        for (int i = t; i < 4096; i += 256) {
            int c = i >> 6, ff = i & 63;
            Wt[ff * 68 + c] = Wk[i];
        }
        for (int rr = rg; rr < 16; rr += 4) {
            int j = idx[(row0 + rr) * nk + k];
            As[rr][f] = (j >= 0) ? X[j * 64 + f] : 0.f;
        }
        __syncthreads();
        const float* wrow = Wt + f * 68;
#pragma unroll
        for (int cq = 0; cq < 64; cq += 4) {
            float4 wq = *(const float4*)(wrow + cq);
#pragma unroll
            for (int rr = 0; rr < 4; rr++) {
                float4 aq = *(const float4*)(&As[rg * 4 + rr][cq]);
                acc[rr] += aq.x * wq.x + aq.y * wq.y + aq.z * wq.z + aq.w * wq.w;
            }
        }
    }
#pragma unroll
    for (int rr = 0; rr < 4; rr++) OUT[(row0 + rg * 4 + rr) * 64 + f] = acc[rr];
}

// ---------------- BN statistics ----------------
__global__ __launch_bounds__(256) void bn_stats(const float* __restrict__ X, const float* __restrict__ X2,
                                                float* __restrict__ stats, int n) {
    int t = threadIdx.x;
    int f = t & 63, g = t >> 6;
    float s = 0.f, ss = 0.f;
    for (int r = blockIdx.x * 4 + g; r < n; r += gridDim.x * 4) {
        float v = X[r * 64 + f];
        if (X2) v += X2[r * 64 + f];
        s += v;
        ss += v * v;
    }
    __shared__ float sh[2][4][64];
    sh[0][g][f] = s;
    sh[1][g][f] = ss;
    __syncthreads();
    if (g == 0) {
        s = sh[0][0][f] + sh[0][1][f] + sh[0][2][f] + sh[0][3][f];
        ss = sh[1][0][f] + sh[1][1][f] + sh[1][2][f] + sh[1][3][f];
        atomicAdd(&stats[f], s);
        atomicAdd(&stats[64 + f], ss);
    }
}

__global__ __launch_bounds__(256) void bn_apply(const float* __restrict__ X, const float* __restrict__ X2,
                                                const float* R, float* OUT,
                                                const float* __restrict__ stats,
                                                const float* __restrict__ gamma,
                                                const float* __restrict__ beta, int n, int do_relu) {
    int i = blockIdx.x * 256 + threadIdx.x;
    if (i >= n * 64) return;
    int f = i & 63;
    float inv_n = 1.f / (float)n;
    float mean = stats[f] * inv_n;
    float var = stats[64 + f] * inv_n - mean * mean;
    float rstd = rsqrtf(var + EPSBN);
    float v = X[i];
    if (X2) v += X2[i];
    v = (v - mean) * rstd * gamma[f] + beta[f];
    if (R) v += R[i];
    if (do_relu) v = fmaxf(v, 0.f);
    OUT[i] = v;
}

// ---------------- prep: fp32 -> fp16 (A split hi/lo; B direct) ----------------
__global__ __launch_bounds__(256) void prep_split(const float* __restrict__ a, const float* __restrict__ b,
                                                  _Float16* __restrict__ Ah, _Float16* __restrict__ Al,
                                                  _Float16* __restrict__ Bh) {
    int i = blockIdx.x * 256 + threadIdx.x;
    if (i >= NPTS * 64) return;
    float av = a[i];
    _Float16 h = (_Float16)av;
    Ah[i] = h;
    Al[i] = (_Float16)(av - (float)h);
    Bh[i] = (_Float16)b[i];
}

// ---------------- V transpose (stage-1): V[key][f] fp32 -> Vt[f][key] fp16 ----------------
__global__ __launch_bounds__(256) void vtrans(const float* __restrict__ V, _Float16* __restrict__ Vt) {
    __shared__ float T[64][65];
    int t = threadIdx.x;
    int k0 = blockIdx.x * 64;
    for (int idx = t; idx < 4096; idx += 256) {
        int r = idx >> 6, c = idx & 63;
        T[r][c] = V[(k0 + r) * 64 + c];
    }
    __syncthreads();
    int f = t >> 2, ks = (t & 3) * 16;
    half8 a, b;
#pragma unroll
    for (int j = 0; j < 8; j++) {
        a[j] = (_Float16)T[ks + j][f];
        b[j] = (_Float16)T[ks + 8 + j][f];
    }
    *(half8*)(Vt + f * NPTS + k0 + ks) = a;
    *(half8*)(Vt + f * NPTS + k0 + ks + 8) = b;
}

// ---------------- V transpose (stage-2): gather via pad_idx into padded [B][64][LPAD2] fp16 ---
__global__ __launch_bounds__(256) void vtrans2(const float* __restrict__ V, const int* __restrict__ pad_idx,
                                               _Float16* __restrict__ Vt2) {
    __shared__ float T[64][65];
    int t = threadIdx.x;
    int b = blockIdx.y;
    int k0 = blockIdx.x * 64;
    const int* prow = pad_idx + b * LQPAD;
    for (int idx = t; idx < 4096; idx += 256) {
        int r = idx >> 6, c = idx & 63;
        int p = k0 + r;
        int flat = (p < LQPAD) ? prow[p] : -1;
        T[r][c] = (flat >= 0) ? V[(size_t)flat * 64 + c] : 0.f;
    }
    __syncthreads();
    int f = t >> 2, ks = (t & 3) * 16;
    half8 a, bb;
#pragma unroll
    for (int j = 0; j < 8; j++) {
        a[j] = (_Float16)T[ks + j][f];
        bb[j] = (_Float16)T[ks + 8 + j][f];
    }
    _Float16* dst = Vt2 + ((size_t)b * 64 + f) * LPAD2 + k0 + ks;
    *(half8*)(dst) = a;
    *(half8*)(dst + 8) = bb;
}

// ---------------- per-batch valid counts from pad_idx ----------------
__global__ __launch_bounds__(256) void count_valid(const int* __restrict__ pad_idx, int* __restrict__ counts) {
    int b = blockIdx.x;
    int t = threadIdx.x;
    int s = 0;
    for (int i = t; i < LQPAD; i += 256) s += (pad_idx[b * LQPAD + i] >= 0) ? 1 : 0;
    for (int off = 32; off > 0; off >>= 1) s += __shfl_xor(s, off);
    if ((t & 63) == 0) atomicAdd(&counts[b], s);
}

// ---------------- Stage-1 flash attention, MFMA (key-split 4 + merge) ----------------
__global__ __launch_bounds__(256) void flash1_mfma(const _Float16* __restrict__ Qh,
                                                   const _Float16* __restrict__ Ql,
                                                   const _Float16* __restrict__ Kh,
                                                   const _Float16* __restrict__ Vt,
                                                   float* __restrict__ Op, float* __restrict__ Ms,
                                                   float* __restrict__ Ls) {
    __shared__ __align__(16) _Float16 KsF[8 * 512];
    __shared__ __align__(16) _Float16 VsF[8 * 512];
    __shared__ __align__(16) _Float16 PTF[4][2 * 512];
    int t = threadIdx.x;
    int lane = t & 63, wv = t >> 6;
    int quad = lane >> 4, qi = lane & 15;
    int qb = blockIdx.x, sp = blockIdx.y;
    int q0w = qb * 64 + wv * 16;
    int qrow = q0w + qi;

    half8 qh[2], ql[2];
#pragma unroll
    for (int s = 0; s < 2; s++) {
        qh[s] = *(const half8*)(Qh + qrow * 64 + s * 32 + quad * 8);
        ql[s] = *(const half8*)(Ql + qrow * 64 + s * 32 + quad * 8);
    }
    floatx4 Oacc[4];
#pragma unroll
    for (int ft = 0; ft < 4; ft++) Oacc[ft] = floatx4{0.f, 0.f, 0.f, 0.f};
    float m_i = -1e30f, l_i = 0.f;

    int k0 = sp * 3072;
    for (int it = 0; it < 48; it++, k0 += 64) {
        __syncthreads();
#pragma unroll
        for (int u = 0; u < 4; u++) {
            int frag = wv + 4 * u;
            if (frag < 8) {
                int kt = frag >> 1, s = frag & 1;
                int key = k0 + kt * 16 + qi;
                int d0 = s * 32 + quad * 8;
                *(half8*)(KsF + frag * 512 + lane * 8) = *(const half8*)(Kh + key * 64 + d0);
            } else {
                int fr = frag - 8;
                int ft = fr >> 1, s = fr & 1;
                int f = ft * 16 + qi;
                int key = k0 + s * 32 + quad * 8;
                *(half8*)(VsF + fr * 512 + lane * 8) = *(const half8*)(Vt + f * NPTS + key);
            }
        }
        __syncthreads();
        floatx4 st[4];
#pragma unroll
        for (int kt = 0; kt < 4; kt++) {
            floatx4 acc = floatx4{0.f, 0.f, 0.f, 0.f};
#pragma unroll
            for (int s = 0; s < 2; s++) {
                half8 a = *(const half8*)(KsF + (kt * 2 + s) * 512 + lane * 8);
                acc = __builtin_amdgcn_mfma_f32_16x16x32_f16(a, qh[s], acc, 0, 0, 0);
                acc = __builtin_amdgcn_mfma_f32_16x16x32_f16(a, ql[s], acc, 0, 0, 0);
            }
            st[kt] = acc;
        }
        float mloc = -1e30f;
#pragma unroll
        for (int kt = 0; kt < 4; kt++)
#pragma unroll
            for (int r = 0; r < 4; r++) mloc = fmaxf(mloc, st[kt][r]);
        mloc = fmaxf(mloc, __shfl_xor(mloc, 16));
        mloc = fmaxf(mloc, __shfl_xor(mloc, 32));
        float m_new = fmaxf(m_i, mloc);
        float alpha = __expf(m_i - m_new);
        float ps = 0.f;
#pragma unroll
        for (int kt = 0; kt < 4; kt++) {
            half4 pk;
#pragma unroll
            for (int r = 0; r < 4; r++) {
                float p = __expf(st[kt][r] - m_new);
                ps += p;
                pk[r] = (_Float16)p;
            }
            int s = kt >> 1;
            int qd2 = (kt & 1) * 2 + (quad >> 1);
            *(half4*)(&PTF[wv][(s * 64 + qd2 * 16 + qi) * 8 + (quad & 1) * 4]) = pk;
        }
        ps += __shfl_xor(ps, 16);
        ps += __shfl_xor(ps, 32);
        l_i = l_i * alpha + ps;
        m_i = m_new;
#pragma unroll
        for (int ft = 0; ft < 4; ft++) Oacc[ft] *= alpha;
        half8 pb[2];
#pragma unroll
        for (int s = 0; s < 2; s++) pb[s] = *(const half8*)(&PTF[wv][(s * 64 + lane) * 8]);
#pragma unroll
        for (int ft = 0; ft < 4; ft++) {
#pragma unroll
            for (int s = 0; s < 2; s++) {
                half8 a = *(const half8*)(VsF + (ft * 2 + s) * 512 + lane * 8);
                Oacc[ft] = __builtin_amdgcn_mfma_f32_16x16x32_f16(a, pb[s], Oacc[ft], 0, 0, 0);
            }
        }
    }
#pragma unroll
    for (int ft = 0; ft < 4; ft++) {
        floatx4 o = Oacc[ft];
        *(floatx4*)(Op + ((size_t)sp * NPTS + q0w + qi) * 64 + ft * 16 + quad * 4) = o;
    }
    if (lane < 16) {
        Ms[sp * NPTS + q0w + lane] = m_i;
        Ls[sp * NPTS + q0w + lane] = l_i;
    }
}

// ---------------- combine key-split partials ----------------
__global__ __launch_bounds__(256) void merge1(const float* __restrict__ Op, const float* __restrict__ Ms,
                                              const float* __restrict__ Ls, float* __restrict__ xr) {
    int i = blockIdx.x * 256 + threadIdx.x;
    int q = i >> 4, f4 = (i & 15) * 4;
    float m[4], M = -1e30f;
#pragma unroll
    for (int s = 0; s < 4; s++) {
        m[s] = Ms[s * NPTS + q];
        M = fmaxf(M, m[s]);
    }
    float L = 0.f;
    float4 acc = {0.f, 0.f, 0.f, 0.f};
#pragma unroll
    for (int s = 0; s < 4; s++) {
        float w = __expf(m[s] - M);
        L += Ls[s * NPTS + q] * w;
        float4 o = *(const float4*)(Op + ((size_t)s * NPTS + q) * 64 + f4);
        acc.x += o.x * w;
        acc.y += o.y * w;
        acc.z += o.z * w;
        acc.w += o.w * w;
    }
    float inv = 1.f / L;
    float4 r = {acc.x * inv, acc.y * inv, acc.z * inv, acc.w * inv};
    *(float4*)(xr + q * 64 + f4) = r;
}

// ---------------- Stage-2 ragged flash attention, MFMA ----------------
// grid (29, 8): x = 64-query block within batch, y = batch. Masking is purely
// positional: pad_idx[b,:c] valid. Invalid K cols stage as 0 (score 0 only
// raises m_new -> harmless); P explicitly zeroed for key_pos >= c.
__global__ __launch_bounds__(256) void flash2_mfma(const _Float16* __restrict__ Qh,
                                                   const _Float16* __restrict__ Ql,
                                                   const _Float16* __restrict__ Kh,
                                                   const _Float16* __restrict__ Vt2,
                                                   const int* __restrict__ pad_idx,
                                                   const int* __restrict__ counts,
                                                   float* __restrict__ O) {
    int b = blockIdx.y;
    int c = counts[b];
    int qb = blockIdx.x;
    if (qb * 64 >= c) return;
    __shared__ __align__(16) _Float16 KsF[8 * 512];
    __shared__ __align__(16) _Float16 VsF[8 * 512];
    __shared__ __align__(16) _Float16 PTF[4][2 * 512];
    int t = threadIdx.x;
    int lane = t & 63, wv = t >> 6;
    int quad = lane >> 4, qi = lane & 15;
    const int* prow = pad_idx + b * LQPAD;
    int p_q = qb * 64 + wv * 16 + qi;
    int flat_q = (p_q < LQPAD) ? prow[p_q] : -1;

    half8 qh[2], ql[2];
#pragma unroll
    for (int s = 0; s < 2; s++) {
        if (flat_q >= 0) {
            qh[s] = *(const half8*)(Qh + (size_t)flat_q * 64 + s * 32 + quad * 8);
            ql[s] = *(const half8*)(Ql + (size_t)flat_q * 64 + s * 32 + quad * 8);
        } else {
            qh[s] = half8{0, 0, 0, 0, 0, 0, 0, 0};
            ql[s] = half8{0, 0, 0, 0, 0, 0, 0, 0};
        }
    }
    floatx4 Oacc[4];
#pragma unroll
    for (int ft = 0; ft < 4; ft++) Oacc[ft] = floatx4{0.f, 0.f, 0.f, 0.f};
    float m_i = -1e30f, l_i = 0.f;
    const _Float16* VtB = Vt2 + (size_t)b * 64 * LPAD2;

    int nt = (c + 63) >> 6;
    for (int it = 0; it < nt; it++) {
        int k0 = it * 64;
        __syncthreads();
#pragma unroll
        for (int u = 0; u < 4; u++) {
            int frag = wv + 4 * u;
            if (frag < 8) {
                int kt = frag >> 1, s = frag & 1;
                int kp = k0 + kt * 16 + qi;
                int flat = (kp < c) ? prow[kp] : -1;
                int d0 = s * 32 + quad * 8;
                half8 kvv = half8{0, 0, 0, 0, 0, 0, 0, 0};
                if (flat >= 0) kvv = *(const half8*)(Kh + (size_t)flat * 64 + d0);
                *(half8*)(KsF + frag * 512 + lane * 8) = kvv;
            } else {
                int fr = frag - 8;
                int ft = fr >> 1, s = fr & 1;
                int f = ft * 16 + qi;
                int key = k0 + s * 32 + quad * 8;
                *(half8*)(VsF + fr * 512 + lane * 8) = *(const half8*)(VtB + f * LPAD2 + key);
            }
        }
        __syncthreads();
        floatx4 st[4];
#pragma unroll
        for (int kt = 0; kt < 4; kt++) {
            floatx4 acc = floatx4{0.f, 0.f, 0.f, 0.f};
#pragma unroll
            for (int s = 0; s < 2; s++) {
                half8 a = *(const half8*)(KsF + (kt * 2 + s) * 512 + lane * 8);
                acc = __builtin_amdgcn_mfma_f32_16x16x32_f16(a, qh[s], acc, 0, 0, 0);
                acc = __builtin_amdgcn_mfma_f32_16x16x32_f16(a, ql[s], acc, 0, 0, 0);
            }
            st[kt] = acc;
        }
        float mloc = -1e30f;
#pragma unroll
        for (int kt = 0; kt < 4; kt++)
#pragma unroll
            for (int r = 0; r < 4; r++) mloc = fmaxf(mloc, st[kt][r]);
        mloc = fmaxf(mloc, __shfl_xor(mloc, 16));
        mloc = fmaxf(mloc, __shfl_xor(mloc, 32));
        float m_new = fmaxf(m_i, mloc);
        float alpha = __expf(m_i - m_new);
        float ps = 0.f;
#pragma unroll
        for (int kt = 0; kt < 4; kt++) {
            half4 pk;
#pragma unroll
            for (int r = 0; r < 4; r++) {
                int kpos = k0 + kt * 16 + quad * 4 + r;
                float p = (kpos < c) ? __expf(st[kt][r] - m_new) : 0.f;
                ps += p;
                pk[r] = (_Float16)p;
            }
            int s = kt >> 1;
            int qd2 = (kt & 1) * 2 + (quad >> 1);
            *(half4*)(&PTF[wv][(s * 64 + qd2 * 16 + qi) * 8 + (quad & 1) * 4]) = pk;
        }
        ps += __shfl_xor(ps, 16);
        ps += __shfl_xor(ps, 32);
        l_i = l_i * alpha + ps;
        m_i = m_new;
#pragma unroll
        for (int ft = 0; ft < 4; ft++) Oacc[ft] *= alpha;
        half8 pb[2];
#pragma unroll
        for (int s = 0; s < 2; s++) pb[s] = *(const half8*)(&PTF[wv][(s * 64 + lane) * 8]);
#pragma unroll
        for (int ft = 0; ft < 4; ft++) {
#pragma unroll
            for (int s = 0; s < 2; s++) {
                half8 a = *(const half8*)(VsF + (ft * 2 + s) * 512 + lane * 8);
                Oacc[ft] = __builtin_amdgcn_mfma_f32_16x16x32_f16(a, pb[s], Oacc[ft], 0, 0, 0);
            }
        }
    }
    if (flat_q >= 0) {
        float inv = 1.f / l_i;
#pragma unroll
        for (int ft = 0; ft < 4; ft++) {
            floatx4 o = Oacc[ft] * inv;
            *(floatx4*)(O + (size_t)flat_q * 64 + ft * 16 + quad * 4) = o;
        }
    }
}

extern "C" void kernel_launch(void* const* d_in, const int* in_sizes, int n_in,
                              void* d_out, int out_size, void* d_ws, size_t ws_size,
                              hipStream_t stream) {
    const float* x_dec = (const float*)d_in[0];
    const float* x_enc = (const float*)d_in[1];
    const float* Wp1 = (const float*)d_in[2];
    const float* Wq = (const float*)d_in[3];
    const float* Wk = (const float*)d_in[4];
    const float* Wv = (const float*)d_in[5];
    const float* Wt_ = (const float*)d_in[6];
    const float* Wq1 = (const float*)d_in[7];
    const float* Wk1 = (const float*)d_in[8];
    const float* Wv1 = (const float*)d_in[9];
    const float* Wdown = (const float*)d_in[10];
    const float* W3t = (const float*)d_in[11];
    const float* W3a = (const float*)d_in[12];
    const float* W3b = (const float*)d_in[13];
    const float* bn_g = (const float*)d_in[14];
    const float* bn_b = (const float*)d_in[15];
    const int* nbr = (const int*)d_in[16];
    const int* kv_nbr = (const int*)d_in[17];
    const int* pad_idx = (const int*)d_in[18];
    float* out = (float*)d_out;
    float* ws = (float*)d_ws;

    const int N = NPTS;
    const size_t BUF = (size_t)N * 64;
    float* xd = ws;                // slot 0
    float* q = ws + BUF;           // slot 1: q / q1; Opart[0]
    float* ke = ws + 2 * BUF;      // slot 2: ke / k1; Opart[1]
    float* ve = ws + 3 * BUF;      // slot 3: ve / v1; Opart[2]
    float* xr = ws + 4 * BUF;      // slot 4: Opart[3] / merged attn / Vt2 fp16 / relu tmp
    float* kv = ws + 5 * BUF;      // slot 5: stage1 Qh/Ql fp16 -> kv -> stage2 Qh1/Ql1 fp16
    float* o2 = ws + 6 * BUF;      // slot 6: stage1 Kh/Vt fp16 -> stage2 Kh1 fp16 -> z
    float* xr2 = ws + 7 * BUF;     // slot 7
    float* z2 = ws + 8 * BUF;      // slot 8: flash2 out, later W3b out
    float* stats = ws + 9 * BUF;   // slot 9: stats(768) + counts(8) + Ms/Ls
    float* Op = q;                 // 4 contiguous split-partials: slots 1..4
    int* counts = (int*)(stats + 768);
    float* Ms = stats + 1024;
    float* Ls = Ms + 4 * NPTS;

    // stage-1 fp16 views
    _Float16* Qh = (_Float16*)kv;
    _Float16* Ql = Qh + BUF;
    _Float16* Kh = (_Float16*)o2;
    _Float16* Vt = Kh + BUF;
    // stage-2 fp16 views (reuse after stage-1 fp16 is dead)
    _Float16* Qh1 = (_Float16*)kv;
    _Float16* Ql1 = Qh1 + BUF;
    _Float16* Kh1 = (_Float16*)o2;
    _Float16* Vt2 = (_Float16*)xr;

    hipMemsetAsync(stats, 0, 1024 * sizeof(float), stream);

    dim3 B(256);
    int gR = N / 16;
    int gS = 64;
    int gE = (N * 64) / 256;

    gemm64<<<gR, B, 0, stream>>>(x_dec, Wp1, xd, N);
    gemm64<<<gR, B, 0, stream>>>(xd, Wq, q, N);
    gemm64<<<gR, B, 0, stream>>>(x_enc, Wk, ke, N);
    gemm64<<<gR, B, 0, stream>>>(x_enc, Wv, ve, N);
    prep_split<<<gE, B, 0, stream>>>(q, ke, Qh, Ql, Kh);
    vtrans<<<N / 64, B, 0, stream>>>(ve, Vt);
    flash1_mfma<<<dim3(N / 64, 4), B, 0, stream>>>(Qh, Ql, Kh, Vt, Op, Ms, Ls);
    merge1<<<(N * 16) / 256, B, 0, stream>>>(Op, Ms, Ls, xr);
    gemm64<<<gR, B, 0, stream>>>(xr, Wt_, xr, N);
    bn_stats<<<gS, B, 0, stream>>>(xr, nullptr, stats + 0, N);
    bn_apply<<<gE, B, 0, stream>>>(xr, nullptr, xd, xd, stats + 0, bn_g + 0, bn_b + 0, N, 0);
    // xr (slot 4) dead from here until res-block -> reused as Vt2

    gemm64<<<gR, B, 0, stream>>>(xd, Wq1, q, N);               // q1
    gconv<<<gR, B, 0, stream>>>(q, kv_nbr, Wdown, kv, N, 8);   // kv (stage-1 fp16 dead)
    bn_stats<<<gS, B, 0, stream>>>(kv, nullptr, stats + 128, N);
    bn_apply<<<gE, B, 0, stream>>>(kv, nullptr, nullptr, kv, stats + 128, bn_g + 64, bn_b + 64, N, 0);
    gemm64<<<gR, B, 0, stream>>>(kv, Wk1, ke, N);              // k1
    gemm64<<<gR, B, 0, stream>>>(kv, Wv1, ve, N);              // v1 (kv dead after)
    prep_split<<<gE, B, 0, stream>>>(q, ke, Qh1, Ql1, Kh1);    // q1 split + k1 fp16
    vtrans2<<<dim3(LPAD2 / 64, 8), B, 0, stream>>>(ve, pad_idx, Vt2);
    count_valid<<<8, B, 0, stream>>>(pad_idx, counts);
    flash2_mfma<<<dim3(LPAD2 / 64, 8), B, 0, stream>>>(Qh1, Ql1, Kh1, Vt2, pad_idx, counts, z2);
    gconv<<<gR, B, 0, stream>>>(z2, nbr, W3t, xr2, N, 27);
    bn_stats<<<gS, B, 0, stream>>>(xr2, nullptr, stats + 256, N);
    bn_apply<<<gE, B, 0, stream>>>(xr2, nullptr, xd, xd, stats + 256, bn_g + 128, bn_b + 128, N, 0);

    bn_stats<<<gS, B, 0, stream>>>(xd, nullptr, stats + 384, N);
    bn_apply<<<gE, B, 0, stream>>>(xd, nullptr, nullptr, xr, stats + 384, bn_g + 192, bn_b + 192, N, 1);
    gconv<<<gR, B, 0, stream>>>(xr, nbr, W3a, o2, N, 27);
    bn_stats<<<gS, B, 0, stream>>>(o2, nullptr, stats + 512, N);
    bn_apply<<<gE, B, 0, stream>>>(o2, nullptr, nullptr, xr2, stats + 512, bn_g + 256, bn_b + 256, N, 1);
    gconv<<<gR, B, 0, stream>>>(xr2, nbr, W3b, z2, N, 27);
    bn_stats<<<gS, B, 0, stream>>>(xd, z2, stats + 640, N);
    bn_apply<<<gE, B, 0, stream>>>(xd, z2, nullptr, out, stats + 640, bn_g + 320, bn_b + 320, N, 1);
}

// Round 4
// 573.591 us; speedup vs baseline: 4.1639x; 1.4209x over previous
//
#include <hip/hip_runtime.h>

#define NPTS 12288
#define LQPAD 1800
#define LPAD2 1856
#define EPSBN 1e-4f

typedef _Float16 half8 __attribute__((ext_vector_type(8)));
typedef _Float16 half4 __attribute__((ext_vector_type(4)));
typedef float floatx4 __attribute__((ext_vector_type(4)));

// ---------------- small GEMM: C[n,64] = A[n,64] @ W[64,64] (+ optional fp16 copy) --------
__global__ __launch_bounds__(256) void gemm64(const float* A, const float* __restrict__ W,
                                              float* C, _Float16* C16, int n) {
    __shared__ __align__(16) float Wt[64 * 68];
    __shared__ __align__(16) float As[16][64];
    int t = threadIdx.x;
    int f = t & 63, rg = t >> 6;
    int row0 = blockIdx.x * 16;
    for (int i = t; i < 4096; i += 256) {
        int c = i >> 6, ff = i & 63;
        Wt[ff * 68 + c] = W[i];
    }
    for (int rr = rg; rr < 16; rr += 4) As[rr][f] = A[(row0 + rr) * 64 + f];
    __syncthreads();
    float acc[4] = {0.f, 0.f, 0.f, 0.f};
    const float* wrow = Wt + f * 68;
#pragma unroll
    for (int cq = 0; cq < 64; cq += 4) {
        float4 wq = *(const float4*)(wrow + cq);
#pragma unroll
        for (int rr = 0; rr < 4; rr++) {
            float4 aq = *(const float4*)(&As[rg * 4 + rr][cq]);
            acc[rr] += aq.x * wq.x + aq.y * wq.y + aq.z * wq.z + aq.w * wq.w;
        }
    }
#pragma unroll
    for (int rr = 0; rr < 4; rr++) {
        C[(row0 + rg * 4 + rr) * 64 + f] = acc[rr];
        if (C16) C16[(row0 + rg * 4 + rr) * 64 + f] = (_Float16)acc[rr];
    }
}

// ---------------- W pack: [ntap][64f][64o] fp32 -> B-fragment-major fp16 ----------------
// Wf[tap][frag(=s*4+ct)][lane][8] ; element j = W[tap][(s*32+quad*8+j)*64 + ct*16 + qi]
__global__ __launch_bounds__(256) void pack_w(const float* __restrict__ W, _Float16* __restrict__ Wf) {
    int tap = blockIdx.x;
    int t = threadIdx.x;
    int lane = t & 63, fg = t >> 6;
    int quad = lane >> 4, qi = lane & 15;
    const float* Wk = W + tap * 4096;
#pragma unroll
    for (int u = 0; u < 2; u++) {
        int frag = fg * 2 + u;
        int s = frag >> 2, ct = frag & 3;
        half8 v;
#pragma unroll
        for (int j = 0; j < 8; j++) v[j] = (_Float16)Wk[(s * 32 + quad * 8 + j) * 64 + ct * 16 + qi];
        *(half8*)(Wf + (size_t)tap * 4096 + frag * 512 + lane * 8) = v;
    }
}

// ---------------- gather conv, MFMA, zero-LDS zero-barrier ----------------
// 64 rows/block (16 per wave). A = per-lane gather from Xh (L2-resident);
// B = packed Wf fragments (identical across waves -> L1 broadcast).
__global__ __launch_bounds__(256) void gconv_mfma(const _Float16* __restrict__ Xh,
                                                  const int* __restrict__ idx,
                                                  const _Float16* __restrict__ Wf,
                                                  float* __restrict__ OUT, int nk) {
    int t = threadIdx.x;
    int lane = t & 63, wv = t >> 6;
    int quad = lane >> 4, qi = lane & 15;
    int row0 = blockIdx.x * 64 + wv * 16;
    floatx4 Oacc[4];
#pragma unroll
    for (int ct = 0; ct < 4; ct++) Oacc[ct] = floatx4{0.f, 0.f, 0.f, 0.f};
    const int* ip = idx + (size_t)(row0 + qi) * nk;
    for (int k = 0; k < nk; k++) {
        int j = ip[k];
        half8 a0 = half8{0, 0, 0, 0, 0, 0, 0, 0};
        half8 a1 = half8{0, 0, 0, 0, 0, 0, 0, 0};
        if (j >= 0) {
            a0 = *(const half8*)(Xh + (size_t)j * 64 + quad * 8);
            a1 = *(const half8*)(Xh + (size_t)j * 64 + 32 + quad * 8);
        }
        const _Float16* wk = Wf + (size_t)k * 4096;
#pragma unroll
        for (int ct = 0; ct < 4; ct++) {
            half8 b0 = *(const half8*)(wk + ct * 512 + lane * 8);
            half8 b1 = *(const half8*)(wk + (4 + ct) * 512 + lane * 8);
            Oacc[ct] = __builtin_amdgcn_mfma_f32_16x16x32_f16(a0, b0, Oacc[ct], 0, 0, 0);
            Oacc[ct] = __builtin_amdgcn_mfma_f32_16x16x32_f16(a1, b1, Oacc[ct], 0, 0, 0);
        }
    }
    int orow = row0 + quad * 4;
#pragma unroll
    for (int ct = 0; ct < 4; ct++)
#pragma unroll
        for (int r = 0; r < 4; r++) OUT[(size_t)(orow + r) * 64 + ct * 16 + qi] = Oacc[ct][r];
}

// ---------------- BN statistics ----------------
__global__ __launch_bounds__(256) void bn_stats(const float* __restrict__ X, const float* __restrict__ X2,
                                                float* __restrict__ stats, int n) {
    int t = threadIdx.x;
    int f = t & 63, g = t >> 6;
    float s = 0.f, ss = 0.f;
    for (int r = blockIdx.x * 4 + g; r < n; r += gridDim.x * 4) {
        float v = X[r * 64 + f];
        if (X2) v += X2[r * 64 + f];
        s += v;
        ss += v * v;
    }
    __shared__ float sh[2][4][64];
    sh[0][g][f] = s;
    sh[1][g][f] = ss;
    __syncthreads();
    if (g == 0) {
        s = sh[0][0][f] + sh[0][1][f] + sh[0][2][f] + sh[0][3][f];
        ss = sh[1][0][f] + sh[1][1][f] + sh[1][2][f] + sh[1][3][f];
        atomicAdd(&stats[f], s);
        atomicAdd(&stats[64 + f], ss);
    }
}

// OUT(f32, opt) / OUT16(fp16, opt) = maybeRelu( BN(X [+ X2]) + (R ? R : 0) )
__global__ __launch_bounds__(256) void bn_apply(const float* __restrict__ X, const float* __restrict__ X2,
                                                const float* R, float* OUT, _Float16* OUT16,
                                                const float* __restrict__ stats,
                                                const float* __restrict__ gamma,
                                                const float* __restrict__ beta, int n, int do_relu) {
    int i = blockIdx.x * 256 + threadIdx.x;
    if (i >= n * 64) return;
    int f = i & 63;
    float inv_n = 1.f / (float)n;
    float mean = stats[f] * inv_n;
    float var = stats[64 + f] * inv_n - mean * mean;
    float rstd = rsqrtf(var + EPSBN);
    float v = X[i];
    if (X2) v += X2[i];
    v = (v - mean) * rstd * gamma[f] + beta[f];
    if (R) v += R[i];
    if (do_relu) v = fmaxf(v, 0.f);
    if (OUT) OUT[i] = v;
    if (OUT16) OUT16[i] = (_Float16)v;
}

// ---------------- prep: fp32 -> fp16 (A split hi/lo; B direct) ----------------
__global__ __launch_bounds__(256) void prep_split(const float* __restrict__ a, const float* __restrict__ b,
                                                  _Float16* __restrict__ Ah, _Float16* __restrict__ Al,
                                                  _Float16* __restrict__ Bh) {
    int i = blockIdx.x * 256 + threadIdx.x;
    if (i >= NPTS * 64) return;
    float av = a[i];
    _Float16 h = (_Float16)av;
    Ah[i] = h;
    Al[i] = (_Float16)(av - (float)h);
    Bh[i] = (_Float16)b[i];
}

// ---------------- V transpose (stage-1): V[key][f] fp32 -> Vt[f][key] fp16 ----------------
__global__ __launch_bounds__(256) void vtrans(const float* __restrict__ V, _Float16* __restrict__ Vt) {
    __shared__ float T[64][65];
    int t = threadIdx.x;
    int k0 = blockIdx.x * 64;
    for (int idx = t; idx < 4096; idx += 256) {
        int r = idx >> 6, c = idx & 63;
        T[r][c] = V[(k0 + r) * 64 + c];
    }
    __syncthreads();
    int f = t >> 2, ks = (t & 3) * 16;
    half8 a, b;
#pragma unroll
    for (int j = 0; j < 8; j++) {
        a[j] = (_Float16)T[ks + j][f];
        b[j] = (_Float16)T[ks + 8 + j][f];
    }
    *(half8*)(Vt + f * NPTS + k0 + ks) = a;
    *(half8*)(Vt + f * NPTS + k0 + ks + 8) = b;
}

// ---------------- V transpose (stage-2): gather via pad_idx into padded [B][64][LPAD2] fp16 ---
__global__ __launch_bounds__(256) void vtrans2(const float* __restrict__ V, const int* __restrict__ pad_idx,
                                               _Float16* __restrict__ Vt2) {
    __shared__ float T[64][65];
    int t = threadIdx.x;
    int b = blockIdx.y;
    int k0 = blockIdx.x * 64;
    const int* prow = pad_idx + b * LQPAD;
    for (int idx = t; idx < 4096; idx += 256) {
        int r = idx >> 6, c = idx & 63;
        int p = k0 + r;
        int flat = (p < LQPAD) ? prow[p] : -1;
        T[r][c] = (flat >= 0) ? V[(size_t)flat * 64 + c] : 0.f;
    }
    __syncthreads();
    int f = t >> 2, ks = (t & 3) * 16;
    half8 a, bb;
#pragma unroll
    for (int j = 0; j < 8; j++) {
        a[j] = (_Float16)T[ks + j][f];
        bb[j] = (_Float16)T[ks + 8 + j][f];
    }
    _Float16* dst = Vt2 + ((size_t)b * 64 + f) * LPAD2 + k0 + ks;
    *(half8*)(dst) = a;
    *(half8*)(dst + 8) = bb;
}

// ---------------- per-batch valid counts from pad_idx ----------------
__global__ __launch_bounds__(256) void count_valid(const int* __restrict__ pad_idx, int* __restrict__ counts) {
    int b = blockIdx.x;
    int t = threadIdx.x;
    int s = 0;
    for (int i = t; i < LQPAD; i += 256) s += (pad_idx[b * LQPAD + i] >= 0) ? 1 : 0;
    for (int off = 32; off > 0; off >>= 1) s += __shfl_xor(s, off);
    if ((t & 63) == 0) atomicAdd(&counts[b], s);
}

// ---------------- Stage-1 flash attention, MFMA (key-split 4 + merge) ----------------
__global__ __launch_bounds__(256) void flash1_mfma(const _Float16* __restrict__ Qh,
                                                   const _Float16* __restrict__ Ql,
                                                   const _Float16* __restrict__ Kh,
                                                   const _Float16* __restrict__ Vt,
                                                   float* __restrict__ Op, float* __restrict__ Ms,
                                                   float* __restrict__ Ls) {
    __shared__ __align__(16) _Float16 KsF[8 * 512];
    __shared__ __align__(16) _Float16 VsF[8 * 512];
    __shared__ __align__(16) _Float16 PTF[4][2 * 512];
    int t = threadIdx.x;
    int lane = t & 63, wv = t >> 6;
    int quad = lane >> 4, qi = lane & 15;
    int qb = blockIdx.x, sp = blockIdx.y;
    int q0w = qb * 64 + wv * 16;
    int qrow = q0w + qi;

    half8 qh[2], ql[2];
#pragma unroll
    for (int s = 0; s < 2; s++) {
        qh[s] = *(const half8*)(Qh + qrow * 64 + s * 32 + quad * 8);
        ql[s] = *(const half8*)(Ql + qrow * 64 + s * 32 + quad * 8);
    }
    floatx4 Oacc[4];
#pragma unroll
    for (int ft = 0; ft < 4; ft++) Oacc[ft] = floatx4{0.f, 0.f, 0.f, 0.f};
    float m_i = -1e30f, l_i = 0.f;

    int k0 = sp * 3072;
    for (int it = 0; it < 48; it++, k0 += 64) {
        __syncthreads();
#pragma unroll
        for (int u = 0; u < 4; u++) {
            int frag = wv + 4 * u;
            if (frag < 8) {
                int kt = frag >> 1, s = frag & 1;
                int key = k0 + kt * 16 + qi;
                int d0 = s * 32 + quad * 8;
                *(half8*)(KsF + frag * 512 + lane * 8) = *(const half8*)(Kh + key * 64 + d0);
            } else {
                int fr = frag - 8;
                int ft = fr >> 1, s = fr & 1;
                int f = ft * 16 + qi;
                int key = k0 + s * 32 + quad * 8;
                *(half8*)(VsF + fr * 512 + lane * 8) = *(const half8*)(Vt + f * NPTS + key);
            }
        }
        __syncthreads();
        floatx4 st[4];
#pragma unroll
        for (int kt = 0; kt < 4; kt++) {
            floatx4 acc = floatx4{0.f, 0.f, 0.f, 0.f};
#pragma unroll
            for (int s = 0; s < 2; s++) {
                half8 a = *(const half8*)(KsF + (kt * 2 + s) * 512 + lane * 8);
                acc = __builtin_amdgcn_mfma_f32_16x16x32_f16(a, qh[s], acc, 0, 0, 0);
                acc = __builtin_amdgcn_mfma_f32_16x16x32_f16(a, ql[s], acc, 0, 0, 0);
            }
            st[kt] = acc;
        }
        float mloc = -1e30f;
#pragma unroll
        for (int kt = 0; kt < 4; kt++)
#pragma unroll
            for (int r = 0; r < 4; r++) mloc = fmaxf(mloc, st[kt][r]);
        mloc = fmaxf(mloc, __shfl_xor(mloc, 16));
        mloc = fmaxf(mloc, __shfl_xor(mloc, 32));
        float m_new = fmaxf(m_i, mloc);
        float alpha = __expf(m_i - m_new);
        float ps = 0.f;
#pragma unroll
        for (int kt = 0; kt < 4; kt++) {
            half4 pk;
#pragma unroll
            for (int r = 0; r < 4; r++) {
                float p = __expf(st[kt][r] - m_new);
                ps += p;
                pk[r] = (_Float16)p;
            }
            int s = kt >> 1;
            int qd2 = (kt & 1) * 2 + (quad >> 1);
            *(half4*)(&PTF[wv][(s * 64 + qd2 * 16 + qi) * 8 + (quad & 1) * 4]) = pk;
        }
        ps += __shfl_xor(ps, 16);
        ps += __shfl_xor(ps, 32);
        l_i = l_i * alpha + ps;
        m_i = m_new;
#pragma unroll
        for (int ft = 0; ft < 4; ft++) Oacc[ft] *= alpha;
        half8 pb[2];
#pragma unroll
        for (int s = 0; s < 2; s++) pb[s] = *(const half8*)(&PTF[wv][(s * 64 + lane) * 8]);
#pragma unroll
        for (int ft = 0; ft < 4; ft++) {
#pragma unroll
            for (int s = 0; s < 2; s++) {
                half8 a = *(const half8*)(VsF + (ft * 2 + s) * 512 + lane * 8);
                Oacc[ft] = __builtin_amdgcn_mfma_f32_16x16x32_f16(a, pb[s], Oacc[ft], 0, 0, 0);
            }
        }
    }
#pragma unroll
    for (int ft = 0; ft < 4; ft++) {
        floatx4 o = Oacc[ft];
        *(floatx4*)(Op + ((size_t)sp * NPTS + q0w + qi) * 64 + ft * 16 + quad * 4) = o;
    }
    if (lane < 16) {
        Ms[sp * NPTS + q0w + lane] = m_i;
        Ls[sp * NPTS + q0w + lane] = l_i;
    }
}

// ---------------- combine key-split partials ----------------
__global__ __launch_bounds__(256) void merge1(const float* __restrict__ Op, const float* __restrict__ Ms,
                                              const float* __restrict__ Ls, float* __restrict__ xr) {
    int i = blockIdx.x * 256 + threadIdx.x;
    int q = i >> 4, f4 = (i & 15) * 4;
    float m[4], M = -1e30f;
#pragma unroll
    for (int s = 0; s < 4; s++) {
        m[s] = Ms[s * NPTS + q];
        M = fmaxf(M, m[s]);
    }
    float L = 0.f;
    float4 acc = {0.f, 0.f, 0.f, 0.f};
#pragma unroll
    for (int s = 0; s < 4; s++) {
        float w = __expf(m[s] - M);
        L += Ls[s * NPTS + q] * w;
        float4 o = *(const float4*)(Op + ((size_t)s * NPTS + q) * 64 + f4);
        acc.x += o.x * w;
        acc.y += o.y * w;
        acc.z += o.z * w;
        acc.w += o.w * w;
    }
    float inv = 1.f / L;
    float4 r = {acc.x * inv, acc.y * inv, acc.z * inv, acc.w * inv};
    *(float4*)(xr + q * 64 + f4) = r;
}

// ---------------- Stage-2 ragged flash attention, MFMA; fp16 output ----------------
__global__ __launch_bounds__(256) void flash2_mfma(const _Float16* __restrict__ Qh,
                                                   const _Float16* __restrict__ Ql,
                                                   const _Float16* __restrict__ Kh,
                                                   const _Float16* __restrict__ Vt2,
                                                   const int* __restrict__ pad_idx,
                                                   const int* __restrict__ counts,
                                                   _Float16* __restrict__ O) {
    int b = blockIdx.y;
    int c = counts[b];
    int qb = blockIdx.x;
    if (qb * 64 >= c) return;
    __shared__ __align__(16) _Float16 KsF[8 * 512];
    __shared__ __align__(16) _Float16 VsF[8 * 512];
    __shared__ __align__(16) _Float16 PTF[4][2 * 512];
    int t = threadIdx.x;
    int lane = t & 63, wv = t >> 6;
    int quad = lane >> 4, qi = lane & 15;
    const int* prow = pad_idx + b * LQPAD;
    int p_q = qb * 64 + wv * 16 + qi;
    int flat_q = (p_q < LQPAD) ? prow[p_q] : -1;

    half8 qh[2], ql[2];
#pragma unroll
    for (int s = 0; s < 2; s++) {
        if (flat_q >= 0) {
            qh[s] = *(const half8*)(Qh + (size_t)flat_q * 64 + s * 32 + quad * 8);
            ql[s] = *(const half8*)(Ql + (size_t)flat_q * 64 + s * 32 + quad * 8);
        } else {
            qh[s] = half8{0, 0, 0, 0, 0, 0, 0, 0};
            ql[s] = half8{0, 0, 0, 0, 0, 0, 0, 0};
        }
    }
    floatx4 Oacc[4];
#pragma unroll
    for (int ft = 0; ft < 4; ft++) Oacc[ft] = floatx4{0.f, 0.f, 0.f, 0.f};
    float m_i = -1e30f, l_i = 0.f;
    const _Float16* VtB = Vt2 + (size_t)b * 64 * LPAD2;

    int nt = (c + 63) >> 6;
    for (int it = 0; it < nt; it++) {
        int k0 = it * 64;
        __syncthreads();
#pragma unroll
        for (int u = 0; u < 4; u++) {
            int frag = wv + 4 * u;
            if (frag < 8) {
                int kt = frag >> 1, s = frag & 1;
                int kp = k0 + kt * 16 + qi;
                int flat = (kp < c) ? prow[kp] : -1;
                int d0 = s * 32 + quad * 8;
                half8 kvv = half8{0, 0, 0, 0, 0, 0, 0, 0};
                if (flat >= 0) kvv = *(const half8*)(Kh + (size_t)flat * 64 + d0);
                *(half8*)(KsF + frag * 512 + lane * 8) = kvv;
            } else {
                int fr = frag - 8;
                int ft = fr >> 1, s = fr & 1;
                int f = ft * 16 + qi;
                int key = k0 + s * 32 + quad * 8;
                *(half8*)(VsF + fr * 512 + lane * 8) = *(const half8*)(VtB + f * LPAD2 + key);
            }
        }
        __syncthreads();
        floatx4 st[4];
#pragma unroll
        for (int kt = 0; kt < 4; kt++) {
            floatx4 acc = floatx4{0.f, 0.f, 0.f, 0.f};
#pragma unroll
            for (int s = 0; s < 2; s++) {
                half8 a = *(const half8*)(KsF + (kt * 2 + s) * 512 + lane * 8);
                acc = __builtin_amdgcn_mfma_f32_16x16x32_f16(a, qh[s], acc, 0, 0, 0);
                acc = __builtin_amdgcn_mfma_f32_16x16x32_f16(a, ql[s], acc, 0, 0, 0);
            }
            st[kt] = acc;
        }
        float mloc = -1e30f;
#pragma unroll
        for (int kt = 0; kt < 4; kt++)
#pragma unroll
            for (int r = 0; r < 4; r++) mloc = fmaxf(mloc, st[kt][r]);
        mloc = fmaxf(mloc, __shfl_xor(mloc, 16));
        mloc = fmaxf(mloc, __shfl_xor(mloc, 32));
        float m_new = fmaxf(m_i, mloc);
        float alpha = __expf(m_i - m_new);
        float ps = 0.f;
#pragma unroll
        for (int kt = 0; kt < 4; kt++) {
            half4 pk;
#pragma unroll
            for (int r = 0; r < 4; r++) {
                int kpos = k0 + kt * 16 + quad * 4 + r;
                float p = (kpos < c) ? __expf(st[kt][r] - m_new) : 0.f;
                ps += p;
                pk[r] = (_Float16)p;
            }
            int s = kt >> 1;
            int qd2 = (kt & 1) * 2 + (quad >> 1);
            *(half4*)(&PTF[wv][(s * 64 + qd2 * 16 + qi) * 8 + (quad & 1) * 4]) = pk;
        }
        ps += __shfl_xor(ps, 16);
        ps += __shfl_xor(ps, 32);
        l_i = l_i * alpha + ps;
        m_i = m_new;
#pragma unroll
        for (int ft = 0; ft < 4; ft++) Oacc[ft] *= alpha;
        half8 pb[2];
#pragma unroll
        for (int s = 0; s < 2; s++) pb[s] = *(const half8*)(&PTF[wv][(s * 64 + lane) * 8]);
#pragma unroll
        for (int ft = 0; ft < 4; ft++) {
#pragma unroll
            for (int s = 0; s < 2; s++) {
                half8 a = *(const half8*)(VsF + (ft * 2 + s) * 512 + lane * 8);
                Oacc[ft] = __builtin_amdgcn_mfma_f32_16x16x32_f16(a, pb[s], Oacc[ft], 0, 0, 0);
            }
        }
    }
    if (flat_q >= 0) {
        float inv = 1.f / l_i;
#pragma unroll
        for (int ft = 0; ft < 4; ft++) {
            half4 o;
#pragma unroll
            for (int r = 0; r < 4; r++) o[r] = (_Float16)(Oacc[ft][r] * inv);
            *(half4*)(O + (size_t)flat_q * 64 + ft * 16 + quad * 4) = o;
        }
    }
}

extern "C" void kernel_launch(void* const* d_in, const int* in_sizes, int n_in,
                              void* d_out, int out_size, void* d_ws, size_t ws_size,
                              hipStream_t stream) {
    const float* x_dec = (const float*)d_in[0];
    const float* x_enc = (const float*)d_in[1];
    const float* Wp1 = (const float*)d_in[2];
    const float* Wq = (const float*)d_in[3];
    const float* Wk = (const float*)d_in[4];
    const float* Wv = (const float*)d_in[5];
    const float* Wt_ = (const float*)d_in[6];
    const float* Wq1 = (const float*)d_in[7];
    const float* Wk1 = (const float*)d_in[8];
    const float* Wv1 = (const float*)d_in[9];
    const float* Wdown = (const float*)d_in[10];
    const float* W3t = (const float*)d_in[11];
    const float* W3a = (const float*)d_in[12];
    const float* W3b = (const float*)d_in[13];
    const float* bn_g = (const float*)d_in[14];
    const float* bn_b = (const float*)d_in[15];
    const int* nbr = (const int*)d_in[16];
    const int* kv_nbr = (const int*)d_in[17];
    const int* pad_idx = (const int*)d_in[18];
    float* out = (float*)d_out;
    float* ws = (float*)d_ws;

    const int N = NPTS;
    const size_t BUF = (size_t)N * 64;
    float* xd = ws;                // slot 0
    float* q = ws + BUF;           // slot 1: q / q1; Op[0]
    float* ke = ws + 2 * BUF;      // slot 2: ke / k1; Op[1]
    float* ve = ws + 3 * BUF;      // slot 3: ve / v1; Op[2]
    float* xr = ws + 4 * BUF;      // slot 4: Op[3]/xr -> q1h fp16 -> Vt2 fp16 -> xrh fp16
    float* kv = ws + 5 * BUF;      // slot 5: Qh/Ql fp16 -> kv -> Qh1/Ql1 fp16 -> Wf_ab fp16
    float* o2 = ws + 6 * BUF;      // slot 6: Kh/Vt fp16 -> Kh1 fp16 -> o2 fp32 (W3a out)
    float* xr2 = ws + 7 * BUF;     // slot 7: xr2 fp32 (W3t out) -> xr2h fp16
    float* z2 = ws + 8 * BUF;      // slot 8: [z2h fp16 | Wf_dt fp16] -> z2 fp32 (W3b out)
    float* stats = ws + 9 * BUF;   // slot 9: stats(768) + counts + Ms/Ls
    float* Op = q;
    int* counts = (int*)(stats + 768);
    float* Ms = stats + 1024;
    float* Ls = Ms + 4 * NPTS;

    // stage-1 fp16 views
    _Float16* Qh = (_Float16*)kv;
    _Float16* Ql = Qh + BUF;
    _Float16* Kh = (_Float16*)o2;
    _Float16* Vt = Kh + BUF;
    // stage-2 fp16 views
    _Float16* Qh1 = (_Float16*)kv;
    _Float16* Ql1 = Qh1 + BUF;
    _Float16* Kh1 = (_Float16*)o2;
    _Float16* Vt2 = (_Float16*)xr;
    // gconv fp16 views
    _Float16* q1h = (_Float16*)xr;       // slot 4 (dead between merge-chain and vtrans2)
    _Float16* z2h = (_Float16*)z2;       // slot 8 first half
    _Float16* Wf_dt = z2h + BUF;         // slot 8 second half: Wdown(8)+W3t(27) packed
    _Float16* Wf_d = Wf_dt;
    _Float16* Wf_3t = Wf_dt + (size_t)8 * 4096;
    _Float16* xrh = (_Float16*)xr;       // slot 4 (after Vt2 dead)
    _Float16* xr2h = (_Float16*)xr2;     // slot 7 first half (after xr2 fp32 dead)
    _Float16* Wf_ab = (_Float16*)kv;     // slot 5 (after flash2): W3a(27)+W3b(27)
    _Float16* Wf_3a = Wf_ab;
    _Float16* Wf_3b = Wf_ab + (size_t)27 * 4096;

    hipMemsetAsync(stats, 0, 1024 * sizeof(float), stream);

    dim3 B(256);
    int gR = N / 16;
    int gC = N / 64;               // 192: gconv_mfma blocks
    int gS = 64;
    int gE = (N * 64) / 256;

    // pack W for the early gathers (slot 8 upper half is free until W3b's output)
    pack_w<<<8, B, 0, stream>>>(Wdown, Wf_d);
    pack_w<<<27, B, 0, stream>>>(W3t, Wf_3t);

    gemm64<<<gR, B, 0, stream>>>(x_dec, Wp1, xd, nullptr, N);
    gemm64<<<gR, B, 0, stream>>>(xd, Wq, q, nullptr, N);
    gemm64<<<gR, B, 0, stream>>>(x_enc, Wk, ke, nullptr, N);
    gemm64<<<gR, B, 0, stream>>>(x_enc, Wv, ve, nullptr, N);
    prep_split<<<gE, B, 0, stream>>>(q, ke, Qh, Ql, Kh);
    vtrans<<<N / 64, B, 0, stream>>>(ve, Vt);
    flash1_mfma<<<dim3(N / 64, 4), B, 0, stream>>>(Qh, Ql, Kh, Vt, Op, Ms, Ls);
    merge1<<<(N * 16) / 256, B, 0, stream>>>(Op, Ms, Ls, xr);
    gemm64<<<gR, B, 0, stream>>>(xr, Wt_, xr, nullptr, N);
    bn_stats<<<gS, B, 0, stream>>>(xr, nullptr, stats + 0, N);
    bn_apply<<<gE, B, 0, stream>>>(xr, nullptr, xd, xd, nullptr, stats + 0, bn_g + 0, bn_b + 0, N, 0);

    gemm64<<<gR, B, 0, stream>>>(xd, Wq1, q, q1h, N);                 // q1 fp32 + fp16
    gconv_mfma<<<gC, B, 0, stream>>>(q1h, kv_nbr, Wf_d, kv, 8);       // stride-2 conv
    bn_stats<<<gS, B, 0, stream>>>(kv, nullptr, stats + 128, N);
    bn_apply<<<gE, B, 0, stream>>>(kv, nullptr, nullptr, kv, nullptr, stats + 128, bn_g + 64, bn_b + 64, N, 0);
    gemm64<<<gR, B, 0, stream>>>(kv, Wk1, ke, nullptr, N);            // k1
    gemm64<<<gR, B, 0, stream>>>(kv, Wv1, ve, nullptr, N);            // v1
    prep_split<<<gE, B, 0, stream>>>(q, ke, Qh1, Ql1, Kh1);           // q1 split + k1 fp16
    vtrans2<<<dim3(LPAD2 / 64, 8), B, 0, stream>>>(ve, pad_idx, Vt2);
    count_valid<<<8, B, 0, stream>>>(pad_idx, counts);
    flash2_mfma<<<dim3(LPAD2 / 64, 8), B, 0, stream>>>(Qh1, Ql1, Kh1, Vt2, pad_idx, counts, z2h);
    // slot 5 now free: pack res-block weights
    pack_w<<<27, B, 0, stream>>>(W3a, Wf_3a);
    pack_w<<<27, B, 0, stream>>>(W3b, Wf_3b);
    gconv_mfma<<<gC, B, 0, stream>>>(z2h, nbr, Wf_3t, xr2, 27);
    bn_stats<<<gS, B, 0, stream>>>(xr2, nullptr, stats + 256, N);
    bn_apply<<<gE, B, 0, stream>>>(xr2, nullptr, xd, xd, nullptr, stats + 256, bn_g + 128, bn_b + 128, N, 0);

    // res block
    bn_stats<<<gS, B, 0, stream>>>(xd, nullptr, stats + 384, N);
    bn_apply<<<gE, B, 0, stream>>>(xd, nullptr, nullptr, nullptr, xrh, stats + 384, bn_g + 192, bn_b + 192, N, 1);
    gconv_mfma<<<gC, B, 0, stream>>>(xrh, nbr, Wf_3a, o2, 27);
    bn_stats<<<gS, B, 0, stream>>>(o2, nullptr, stats + 512, N);
    bn_apply<<<gE, B, 0, stream>>>(o2, nullptr, nullptr, nullptr, xr2h, stats + 512, bn_g + 256, bn_b + 256, N, 1);
    gconv_mfma<<<gC, B, 0, stream>>>(xr2h, nbr, Wf_3b, z2, 27);
    bn_stats<<<gS, B, 0, stream>>>(xd, z2, stats + 640, N);
    bn_apply<<<gE, B, 0, stream>>>(xd, z2, nullptr, out, nullptr, stats + 640, bn_g + 320, bn_b + 320, N, 1);
}